// Round 2
// baseline (1045.758 us; speedup 1.0000x reference)
//
#include <hip/hip_runtime.h>
#include <stdint.h>

typedef __attribute__((ext_vector_type(8))) short short8;
typedef __attribute__((ext_vector_type(4))) float float4v;

__device__ __forceinline__ float bf2f(unsigned short s) {
    union { unsigned int u; float f; } c; c.u = ((unsigned int)s) << 16; return c.f;
}
__device__ __forceinline__ unsigned short f2bf(float f) {
    union { float f; unsigned int u; } c; c.f = f;
    unsigned int x = c.u;
    unsigned int r = x + 0x7fffu + ((x >> 16) & 1u);   // RNE
    return (unsigned short)(r >> 16);
}

// ---------------- CSR build ----------------

__global__ __launch_bounds__(256) void k_hist(const int* __restrict__ dst, int nE,
                                              int* __restrict__ cnt) {
    int e = blockIdx.x * 256 + threadIdx.x;
    if (e < nE) atomicAdd(&cnt[dst[e]], 1);
}

__global__ __launch_bounds__(256) void k_scan_local(const int* __restrict__ cnt, int N,
                                                    int* __restrict__ off,
                                                    int* __restrict__ part) {
    __shared__ int s[256];
    int t = threadIdx.x;
    int i = blockIdx.x * 256 + t;
    int v = (i < N) ? cnt[i] : 0;
    s[t] = v;
    __syncthreads();
    for (int o = 1; o < 256; o <<= 1) {
        int x = (t >= o) ? s[t - o] : 0;
        __syncthreads();
        s[t] += x;
        __syncthreads();
    }
    if (i < N) off[i] = s[t] - v;          // exclusive
    if (t == 255) part[blockIdx.x] = s[255];
}

__global__ __launch_bounds__(512) void k_scan_part(int* __restrict__ part, int nb) {
    __shared__ int s[512];
    int t = threadIdx.x;
    int v = (t < nb) ? part[t] : 0;
    s[t] = v;
    __syncthreads();
    for (int o = 1; o < 512; o <<= 1) {
        int x = (t >= o) ? s[t - o] : 0;
        __syncthreads();
        s[t] += x;
        __syncthreads();
    }
    if (t < nb) part[t] = s[t] - v;        // exclusive
    if (t == nb - 1) part[nb] = s[t];      // grand total
}

__global__ __launch_bounds__(256) void k_scan_add(int* __restrict__ off,
                                                  const int* __restrict__ part, int N,
                                                  int* __restrict__ cur) {
    int i = blockIdx.x * 256 + threadIdx.x;
    if (i < N) {
        int v = off[i] + part[i >> 8];
        off[i] = v;
        cur[i] = v;
    } else if (i == N) {
        off[N] = part[(N + 255) >> 8];
    }
}

__global__ __launch_bounds__(256) void k_scatter(const int* __restrict__ src,
                                                 const int* __restrict__ dst, int nE,
                                                 int* __restrict__ cur,
                                                 int* __restrict__ esrc) {
    int e = blockIdx.x * 256 + threadIdx.x;
    if (e < nE) {
        int p = atomicAdd(&cur[dst[e]], 1);
        esrc[p] = src[e];
    }
}

// ---------------- weight prep: fp32 W[k][n] -> bf16 hi/lo transposed [n][k] ---------

__global__ __launch_bounds__(256) void k_wprep(const float* __restrict__ W,
                                               unsigned short* __restrict__ hiT,
                                               unsigned short* __restrict__ loT,
                                               int N, int NPAD) {
    int idx = blockIdx.x * 256 + threadIdx.x;
    if (idx >= NPAD * 128) return;
    int n = idx >> 7, k = idx & 127;
    float w = (n < N) ? W[k * N + n] : 0.f;
    unsigned short h = f2bf(w);
    float r = w - bf2f(h);
    hiT[idx] = h;
    loT[idx] = f2bf(r);
}

// ---------------- aggregation: a = (1+eps)*h + sum_{j->i} h_j ; emit bf16 hi/lo -----

__global__ __launch_bounds__(256) void k_aggr(const float2* __restrict__ hin,
                                              const int* __restrict__ off,
                                              const int* __restrict__ esrc,
                                              const float* __restrict__ epsp,
                                              unsigned int* __restrict__ Ahi,
                                              unsigned int* __restrict__ Alo, int M) {
    int wave = threadIdx.x >> 6, lane = threadIdx.x & 63;
    int node = blockIdx.x * 4 + wave;
    if (node >= M) return;
    float ep = 1.0f + epsp[0];
    float2 v = hin[node * 64 + lane];
    float a0 = ep * v.x, a1 = ep * v.y;
    int i = off[node], e = off[node + 1];
    for (; i + 4 <= e; i += 4) {
        int s0 = esrc[i], s1 = esrc[i + 1], s2 = esrc[i + 2], s3 = esrc[i + 3];
        float2 v0 = hin[s0 * 64 + lane];
        float2 v1 = hin[s1 * 64 + lane];
        float2 v2 = hin[s2 * 64 + lane];
        float2 v3 = hin[s3 * 64 + lane];
        a0 += v0.x + v1.x + v2.x + v3.x;
        a1 += v0.y + v1.y + v2.y + v3.y;
    }
    for (; i < e; ++i) {
        float2 v0 = hin[esrc[i] * 64 + lane];
        a0 += v0.x;
        a1 += v0.y;
    }
    unsigned short h0 = f2bf(a0), h1 = f2bf(a1);
    unsigned short l0 = f2bf(a0 - bf2f(h0)), l1 = f2bf(a1 - bf2f(h1));
    Ahi[node * 64 + lane] = ((unsigned int)h1 << 16) | h0;
    Alo[node * 64 + lane] = ((unsigned int)l1 << 16) | l0;
}

// ---------------- GEMM: C = A @ W + b via bf16x3 MFMA, fp32 accumulate --------------
// A given as hi/lo bf16 row-major [M][128]; W given as hi/lo bf16 transposed [n][128].
// OUTMODE: 0 = write hi/lo bf16 [M][128] (feeds next GEMM)
//          1 = write fp32 [M][128]       (feeds next aggregation)
//          2 = write fp32 [M][40]        (logits; cols >= 40 dropped)

template <int NT, bool RELU, int OUTMODE>
__global__ __launch_bounds__(256) void k_gemm(const unsigned short* __restrict__ AhiS,
                                              const unsigned short* __restrict__ AloS,
                                              const unsigned short* __restrict__ WhiT,
                                              const unsigned short* __restrict__ WloT,
                                              const float* __restrict__ Bias,
                                              unsigned short* __restrict__ OutHi,
                                              unsigned short* __restrict__ OutLo,
                                              float* __restrict__ OutF, int M) {
    int t = threadIdx.x, wave = t >> 6, lane = t & 63;
    int lm = lane & 15, lg = lane >> 4;
    int r0 = blockIdx.x * 64 + wave * 16;
    if (r0 >= M) return;   // M % 16 == 0, so no partial wave

    const short* Ah = (const short*)AhiS + (r0 + lm) * 128 + lg * 8;
    const short* Al = (const short*)AloS + (r0 + lm) * 128 + lg * 8;
    short8 ah[4], al[4];
#pragma unroll
    for (int kb = 0; kb < 4; ++kb) {
        ah[kb] = *(const short8*)(Ah + kb * 32);
        al[kb] = *(const short8*)(Al + kb * 32);
    }
    float4v acc[NT];
#pragma unroll
    for (int nt = 0; nt < NT; ++nt) acc[nt] = (float4v){0.f, 0.f, 0.f, 0.f};
#pragma unroll
    for (int nt = 0; nt < NT; ++nt) {
        const short* Wh = (const short*)WhiT + (nt * 16 + lm) * 128 + lg * 8;
        const short* Wl = (const short*)WloT + (nt * 16 + lm) * 128 + lg * 8;
#pragma unroll
        for (int kb = 0; kb < 4; ++kb) {
            short8 wh = *(const short8*)(Wh + kb * 32);
            short8 wl = *(const short8*)(Wl + kb * 32);
            acc[nt] = __builtin_amdgcn_mfma_f32_16x16x32_bf16(ah[kb], wh, acc[nt], 0, 0, 0);
            acc[nt] = __builtin_amdgcn_mfma_f32_16x16x32_bf16(al[kb], wh, acc[nt], 0, 0, 0);
            acc[nt] = __builtin_amdgcn_mfma_f32_16x16x32_bf16(ah[kb], wl, acc[nt], 0, 0, 0);
        }
    }
#pragma unroll
    for (int nt = 0; nt < NT; ++nt) {
        int col = nt * 16 + lm;
        float b = (OUTMODE == 2) ? (col < 40 ? Bias[col] : 0.f) : Bias[col];
#pragma unroll
        for (int r = 0; r < 4; ++r) {
            int row = r0 + lg * 4 + r;
            float v = acc[nt][r] + b;
            if (RELU) v = v > 0.f ? v : 0.f;
            if (OUTMODE == 0) {
                unsigned short h = f2bf(v);
                OutHi[row * 128 + col] = h;
                OutLo[row * 128 + col] = f2bf(v - bf2f(h));
            } else if (OUTMODE == 1) {
                OutF[row * 128 + col] = v;
            } else {
                if (col < 40) OutF[row * 40 + col] = v;
            }
        }
    }
}

// ---------------- log_softmax over 40 cols (fp32 in/out) ----------------

__global__ __launch_bounds__(256) void k_lsm(const float* __restrict__ logits,
                                             float* __restrict__ out, int M) {
    int wave = threadIdx.x >> 6, lane = threadIdx.x & 63;
    int row = blockIdx.x * 4 + wave;
    if (row >= M) return;
    float v = (lane < 40) ? logits[row * 40 + lane] : -1e30f;
    float m = v;
#pragma unroll
    for (int o = 32; o >= 1; o >>= 1) m = fmaxf(m, __shfl_xor(m, o, 64));
    float ex = (lane < 40) ? expf(v - m) : 0.f;
    float s = ex;
#pragma unroll
    for (int o = 32; o >= 1; o >>= 1) s += __shfl_xor(s, o, 64);
    float ls = logf(s);
    if (lane < 40) out[row * 40 + lane] = v - m - ls;
}

// ---------------- launch ----------------

extern "C" void kernel_launch(void* const* d_in, const int* in_sizes, int n_in,
                              void* d_out, int out_size, void* d_ws, size_t ws_size,
                              hipStream_t stream) {
    const float* x     = (const float*)d_in[0];
    const int*   edges = (const int*)d_in[1];
    const float* W1_0 = (const float*)d_in[2];
    const float* b1_0 = (const float*)d_in[3];
    const float* W2_0 = (const float*)d_in[4];
    const float* b2_0 = (const float*)d_in[5];
    const float* eps0 = (const float*)d_in[6];
    const float* W1_1 = (const float*)d_in[7];
    const float* b1_1 = (const float*)d_in[8];
    const float* W2_1 = (const float*)d_in[9];
    const float* b2_1 = (const float*)d_in[10];
    const float* eps1 = (const float*)d_in[11];
    const float* W1_2 = (const float*)d_in[12];
    const float* b1_2 = (const float*)d_in[13];
    const float* W2_2 = (const float*)d_in[14];
    const float* b2_2 = (const float*)d_in[15];
    const float* eps2 = (const float*)d_in[16];

    int M  = in_sizes[0] / 128;   // 100000 nodes
    int nE = in_sizes[1] / 2;     // 1600000 edges
    const int* e_src = edges;
    const int* e_dst = edges + nE;

    char* ws = (char*)d_ws;
    size_t o = 0;
    auto alloc = [&](size_t bytes) {
        size_t p = o;
        o = (o + bytes + 511) & ~(size_t)511;
        return ws + p;
    };
    int* cnt  = (int*)alloc((size_t)M * 4);
    int* off  = (int*)alloc((size_t)(M + 1) * 4);
    int* part = (int*)alloc(513 * 4);
    int* cur  = (int*)alloc((size_t)M * 4);
    int* esrc = (int*)alloc((size_t)nE * 4);
    // weight prep buffers (bf16 hi/lo transposed)
    unsigned short* w1h[3]; unsigned short* w1l[3];
    unsigned short* w2h[3]; unsigned short* w2l[3];
    for (int L = 0; L < 3; ++L) {
        w1h[L] = (unsigned short*)alloc(128 * 128 * 2);
        w1l[L] = (unsigned short*)alloc(128 * 128 * 2);
        int npad = (L == 2) ? 48 : 128;
        w2h[L] = (unsigned short*)alloc((size_t)npad * 128 * 2);
        w2l[L] = (unsigned short*)alloc((size_t)npad * 128 * 2);
    }
    unsigned short* Ahi = (unsigned short*)alloc((size_t)M * 128 * 2);
    unsigned short* Alo = (unsigned short*)alloc((size_t)M * 128 * 2);
    unsigned short* Hhi = (unsigned short*)alloc((size_t)M * 128 * 2);
    unsigned short* Hlo = (unsigned short*)alloc((size_t)M * 128 * 2);
    float*          Hf  = (float*)alloc((size_t)M * 128 * 4);
    float*          logit = (float*)Ahi;   // alias: Ahi dead once layer-2 GEMM1 ran
    (void)ws_size; (void)n_in; (void)out_size;

    hipMemsetAsync(cnt, 0, (size_t)M * 4, stream);

    int nbE = (nE + 255) / 256;
    int nbN = (M + 255) / 256;          // 391
    k_hist<<<nbE, 256, 0, stream>>>(e_dst, nE, cnt);
    k_scan_local<<<nbN, 256, 0, stream>>>(cnt, M, off, part);
    k_scan_part<<<1, 512, 0, stream>>>(part, nbN);
    k_scan_add<<<(M + 1 + 255) / 256, 256, 0, stream>>>(off, part, M, cur);
    k_scatter<<<nbE, 256, 0, stream>>>(e_src, e_dst, nE, cur, esrc);

    // weight prep (6 small launches)
    k_wprep<<<64, 256, 0, stream>>>(W1_0, w1h[0], w1l[0], 128, 128);
    k_wprep<<<64, 256, 0, stream>>>(W2_0, w2h[0], w2l[0], 128, 128);
    k_wprep<<<64, 256, 0, stream>>>(W1_1, w1h[1], w1l[1], 128, 128);
    k_wprep<<<64, 256, 0, stream>>>(W2_1, w2h[1], w2l[1], 128, 128);
    k_wprep<<<64, 256, 0, stream>>>(W1_2, w1h[2], w1l[2], 128, 128);
    k_wprep<<<24, 256, 0, stream>>>(W2_2, w2h[2], w2l[2], 40, 48);

    int gAgg  = (M + 3) / 4;
    int gGemm = (M + 63) / 64;

    // layer 0
    k_aggr<<<gAgg, 256, 0, stream>>>((const float2*)x, off, esrc, eps0,
                                     (unsigned int*)Ahi, (unsigned int*)Alo, M);
    k_gemm<8, true, 0><<<gGemm, 256, 0, stream>>>(Ahi, Alo, w1h[0], w1l[0], b1_0,
                                                  Hhi, Hlo, nullptr, M);
    k_gemm<8, true, 1><<<gGemm, 256, 0, stream>>>(Hhi, Hlo, w2h[0], w2l[0], b2_0,
                                                  nullptr, nullptr, Hf, M);
    // layer 1
    k_aggr<<<gAgg, 256, 0, stream>>>((const float2*)Hf, off, esrc, eps1,
                                     (unsigned int*)Ahi, (unsigned int*)Alo, M);
    k_gemm<8, true, 0><<<gGemm, 256, 0, stream>>>(Ahi, Alo, w1h[1], w1l[1], b1_1,
                                                  Hhi, Hlo, nullptr, M);
    k_gemm<8, true, 1><<<gGemm, 256, 0, stream>>>(Hhi, Hlo, w2h[1], w2l[1], b2_1,
                                                  nullptr, nullptr, Hf, M);
    // layer 2
    k_aggr<<<gAgg, 256, 0, stream>>>((const float2*)Hf, off, esrc, eps2,
                                     (unsigned int*)Ahi, (unsigned int*)Alo, M);
    k_gemm<8, true, 0><<<gGemm, 256, 0, stream>>>(Ahi, Alo, w1h[2], w1l[2], b1_2,
                                                  Hhi, Hlo, nullptr, M);
    k_gemm<3, false, 2><<<gGemm, 256, 0, stream>>>(Hhi, Hlo, w2h[2], w2l[2], b2_2,
                                                   nullptr, nullptr, logit, M);
    k_lsm<<<gAgg, 256, 0, stream>>>(logit, (float*)d_out, M);
}

// Round 3
// 952.542 us; speedup vs baseline: 1.0979x; 1.0979x over previous
//
#include <hip/hip_runtime.h>
#include <stdint.h>

typedef __attribute__((ext_vector_type(8))) short short8;
typedef __attribute__((ext_vector_type(4))) float float4v;

__device__ __forceinline__ float bf2f(unsigned short s) {
    union { unsigned int u; float f; } c; c.u = ((unsigned int)s) << 16; return c.f;
}
__device__ __forceinline__ unsigned short f2bf(float f) {
    union { float f; unsigned int u; } c; c.f = f;
    unsigned int x = c.u;
    unsigned int r = x + 0x7fffu + ((x >> 16) & 1u);   // RNE
    return (unsigned short)(r >> 16);
}

// ================= CSR build via bucket sort (bucket = dst>>8) =================
// pass A: global per-bucket histogram (LDS-staged)
__global__ __launch_bounds__(256) void bs_count(const int* __restrict__ dst, int nE,
                                                int* __restrict__ bucketCnt) {
    __shared__ int c[512];
    int t = threadIdx.x;
    for (int i = t; i < 512; i += 256) c[i] = 0;
    __syncthreads();
    int base = blockIdx.x * 4096;
    for (int i = t; i < 4096; i += 256) {
        int e = base + i;
        if (e < nE) atomicAdd(&c[dst[e] >> 8], 1);
    }
    __syncthreads();
    for (int i = t; i < 512; i += 256)
        if (c[i]) atomicAdd(&bucketCnt[i], c[i]);
}

// pass B: scan buckets, init cursors, set off[M]=nE
__global__ __launch_bounds__(512) void bs_scan(const int* __restrict__ bucketCnt,
                                               int* __restrict__ bucketBase,
                                               int* __restrict__ bucketCur,
                                               int* __restrict__ off, int M, int nE) {
    __shared__ int s[512];
    int t = threadIdx.x;
    int v = bucketCnt[t];
    s[t] = v;
    __syncthreads();
    for (int o = 1; o < 512; o <<= 1) {
        int x = (t >= o) ? s[t - o] : 0;
        __syncthreads();
        s[t] += x;
        __syncthreads();
    }
    bucketBase[t] = s[t] - v;
    bucketCur[t] = s[t] - v;
    if (t == 511) bucketBase[512] = s[511];
    if (t == 0) off[M] = nE;
}

// pass C: scatter edges into bucket regions, LDS-reordered for coalescing.
// packed entry: src (bits 0..16) | (dst&255)<<17
__global__ __launch_bounds__(512) void bs_scatter(const int* __restrict__ src,
                                                  const int* __restrict__ dst, int nE,
                                                  int* __restrict__ bucketCur,
                                                  unsigned int* __restrict__ ebuf) {
    __shared__ int cnt[512];
    __shared__ int excl[512];
    __shared__ int chunk[512];
    __shared__ unsigned int buf[4096];
    __shared__ unsigned short bkt[4096];
    int t = threadIdx.x;
    cnt[t] = 0;
    __syncthreads();
    int base = blockIdx.x * 4096;
    int n = nE - base; if (n > 4096) n = 4096;
    unsigned int pk[8]; int bk[8]; int rk[8];
#pragma unroll
    for (int u = 0; u < 8; ++u) {
        int i = t + u * 512;
        if (i < n) {
            int e = base + i;
            int d = dst[e];
            int b = d >> 8;
            bk[u] = b;
            pk[u] = (unsigned int)src[e] | ((unsigned int)(d & 255) << 17);
            rk[u] = atomicAdd(&cnt[b], 1);
        } else bk[u] = -1;
    }
    __syncthreads();
    excl[t] = cnt[t];
    __syncthreads();
    for (int o = 1; o < 512; o <<= 1) {
        int x = (t >= o) ? excl[t - o] : 0;
        __syncthreads();
        excl[t] += x;
        __syncthreads();
    }
    int ex = excl[t] - cnt[t];
    __syncthreads();
    excl[t] = ex;
    if (cnt[t]) chunk[t] = atomicAdd(&bucketCur[t], cnt[t]);
    __syncthreads();
#pragma unroll
    for (int u = 0; u < 8; ++u) {
        if (bk[u] >= 0) {
            int lp = excl[bk[u]] + rk[u];
            buf[lp] = pk[u];
            bkt[lp] = (unsigned short)bk[u];
        }
    }
    __syncthreads();
    for (int i = t; i < n; i += 512) {
        int b = bkt[i];
        ebuf[chunk[b] + (i - excl[b])] = buf[i];
    }
}

// pass D: per-bucket counting sort -> off[] and esrc[] (fully coalesced I/O)
__global__ __launch_bounds__(512) void bs_build(const unsigned int* __restrict__ ebuf,
                                                const int* __restrict__ bucketBase,
                                                int* __restrict__ off,
                                                int* __restrict__ esrc, int M) {
    __shared__ int cnt[256];
    __shared__ int excl[256];
    __shared__ int obuf[5120];
    int t = threadIdx.x, b = blockIdx.x;
    int base = bucketBase[b];
    int n = bucketBase[b + 1] - base;
    if (t < 256) cnt[t] = 0;
    __syncthreads();
    unsigned int pk[10]; int dl[10]; int rk[10];
#pragma unroll
    for (int u = 0; u < 10; ++u) {
        int i = t + u * 512;
        if (i < n) {
            unsigned int p = ebuf[base + i];
            pk[u] = p;
            int d = (p >> 17) & 255;
            dl[u] = d;
            rk[u] = atomicAdd(&cnt[d], 1);
        } else dl[u] = -1;
    }
    __syncthreads();
    if (t < 256) excl[t] = cnt[t];
    __syncthreads();
    for (int o = 1; o < 256; o <<= 1) {
        int x = (t < 256 && t >= o) ? excl[t - o] : 0;
        __syncthreads();
        if (t < 256) excl[t] += x;
        __syncthreads();
    }
    if (t < 256) {
        int ex = excl[t] - cnt[t];
        int node = b * 256 + t;
        if (node < M) off[node] = base + ex;
        excl[t] = ex;
    }
    __syncthreads();
#pragma unroll
    for (int u = 0; u < 10; ++u) {
        if (dl[u] >= 0) {
            int lp = excl[dl[u]] + rk[u];
            if (lp < 5120) obuf[lp] = (int)(pk[u] & 0x1FFFF);
        }
    }
    __syncthreads();
    for (int i = t; i < n; i += 512) esrc[base + i] = obuf[i];
}

// ============ weight prep: fp32 W[k][n] -> bf16 hi/lo transposed [n][k] ============
__global__ __launch_bounds__(256) void k_wprep(const float* __restrict__ W,
                                               unsigned short* __restrict__ hiT,
                                               unsigned short* __restrict__ loT,
                                               int N, int NPAD) {
    int idx = blockIdx.x * 256 + threadIdx.x;
    if (idx >= NPAD * 128) return;
    int n = idx >> 7, k = idx & 127;
    float w = (n < N) ? W[k * N + n] : 0.f;
    unsigned short h = f2bf(w);
    hiT[idx] = h;
    loT[idx] = f2bf(w - bf2f(h));
}

// ======== fused layer: gather-aggregate + MLP1(relu) + MLP2 (bf16x3 MFMA) ==========
// Wave-private 16-row slabs in LDS; no barriers needed.
// LOGITS=false: OutF = fp32 [M][128]; LOGITS=true: OutF = fp32 [M][40]

template <int NT2, bool RELU_OUT, bool LOGITS>
__global__ __launch_bounds__(256) void k_layer(const float2* __restrict__ Hin,
                                               const int* __restrict__ off,
                                               const int* __restrict__ esrc,
                                               const float* __restrict__ epsp,
                                               const unsigned short* __restrict__ W1h,
                                               const unsigned short* __restrict__ W1l,
                                               const float* __restrict__ B1,
                                               const unsigned short* __restrict__ W2h,
                                               const unsigned short* __restrict__ W2l,
                                               const float* __restrict__ B2,
                                               float* __restrict__ OutF, int M) {
    __shared__ short Ahs[64 * 136];
    __shared__ short Als[64 * 136];
    int t = threadIdx.x, w = t >> 6, lane = t & 63;
    int lm = lane & 15, lg = lane >> 4;
    int r0 = blockIdx.x * 64;
    float ep = 1.0f + epsp[0];

    // ---- gather-aggregate 16 nodes per wave, fp32, split to bf16 hi/lo in LDS ----
    for (int j = 0; j < 16; ++j) {
        int node = r0 + w * 16 + j;
        if (node >= M) break;                 // wave-uniform
        float2 a = Hin[node * 64 + lane];
        float a0 = ep * a.x, a1 = ep * a.y;
        int i = off[node], e = off[node + 1];
        for (; i + 8 <= e; i += 8) {
            int s0 = esrc[i],     s1 = esrc[i + 1], s2 = esrc[i + 2], s3 = esrc[i + 3];
            int s4 = esrc[i + 4], s5 = esrc[i + 5], s6 = esrc[i + 6], s7 = esrc[i + 7];
            float2 v0 = Hin[s0 * 64 + lane], v1 = Hin[s1 * 64 + lane];
            float2 v2 = Hin[s2 * 64 + lane], v3 = Hin[s3 * 64 + lane];
            float2 v4 = Hin[s4 * 64 + lane], v5 = Hin[s5 * 64 + lane];
            float2 v6 = Hin[s6 * 64 + lane], v7 = Hin[s7 * 64 + lane];
            a0 += v0.x + v1.x + v2.x + v3.x + v4.x + v5.x + v6.x + v7.x;
            a1 += v0.y + v1.y + v2.y + v3.y + v4.y + v5.y + v6.y + v7.y;
        }
        for (; i < e; ++i) {
            float2 v = Hin[esrc[i] * 64 + lane];
            a0 += v.x;
            a1 += v.y;
        }
        unsigned short h0 = f2bf(a0), h1 = f2bf(a1);
        unsigned short l0 = f2bf(a0 - bf2f(h0)), l1 = f2bf(a1 - bf2f(h1));
        int row = w * 16 + j;
        *(unsigned int*)&Ahs[row * 136 + lane * 2] = ((unsigned int)h1 << 16) | h0;
        *(unsigned int*)&Als[row * 136 + lane * 2] = ((unsigned int)l1 << 16) | l0;
    }

    if (r0 + w * 16 >= M) return;             // wave-uniform; no barriers in kernel

    // ---- GEMM1: H = relu(A @ W1 + b1), bf16x3 ----
    short8 ah[4], al[4];
#pragma unroll
    for (int kb = 0; kb < 4; ++kb) {
        ah[kb] = *(const short8*)&Ahs[(w * 16 + lm) * 136 + kb * 32 + lg * 8];
        al[kb] = *(const short8*)&Als[(w * 16 + lm) * 136 + kb * 32 + lg * 8];
    }
    float4v acc[8];
#pragma unroll
    for (int nt = 0; nt < 8; ++nt) acc[nt] = (float4v){0.f, 0.f, 0.f, 0.f};
#pragma unroll
    for (int nt = 0; nt < 8; ++nt) {
        const short* Wh = (const short*)W1h + (nt * 16 + lm) * 128 + lg * 8;
        const short* Wl = (const short*)W1l + (nt * 16 + lm) * 128 + lg * 8;
#pragma unroll
        for (int kb = 0; kb < 4; ++kb) {
            short8 wh = *(const short8*)(Wh + kb * 32);
            short8 wl = *(const short8*)(Wl + kb * 32);
            acc[nt] = __builtin_amdgcn_mfma_f32_16x16x32_bf16(ah[kb], wh, acc[nt], 0, 0, 0);
            acc[nt] = __builtin_amdgcn_mfma_f32_16x16x32_bf16(al[kb], wh, acc[nt], 0, 0, 0);
            acc[nt] = __builtin_amdgcn_mfma_f32_16x16x32_bf16(ah[kb], wl, acc[nt], 0, 0, 0);
        }
    }
    // bias + relu + hi/lo split back into the (wave-private) LDS slab
#pragma unroll
    for (int nt = 0; nt < 8; ++nt) {
        float b = B1[nt * 16 + lm];
#pragma unroll
        for (int r = 0; r < 4; ++r) {
            float v = acc[nt][r] + b;
            v = v > 0.f ? v : 0.f;
            unsigned short h = f2bf(v);
            int row = w * 16 + lg * 4 + r;
            Ahs[row * 136 + nt * 16 + lm] = (short)h;
            Als[row * 136 + nt * 16 + lm] = (short)f2bf(v - bf2f(h));
        }
    }

    // ---- GEMM2: Out = H @ W2 + b2 (optionally relu), bf16x3 ----
    short8 hh[4], hl[4];
#pragma unroll
    for (int kb = 0; kb < 4; ++kb) {
        hh[kb] = *(const short8*)&Ahs[(w * 16 + lm) * 136 + kb * 32 + lg * 8];
        hl[kb] = *(const short8*)&Als[(w * 16 + lm) * 136 + kb * 32 + lg * 8];
    }
    float4v acc2[NT2];
#pragma unroll
    for (int nt = 0; nt < NT2; ++nt) acc2[nt] = (float4v){0.f, 0.f, 0.f, 0.f};
#pragma unroll
    for (int nt = 0; nt < NT2; ++nt) {
        const short* Wh = (const short*)W2h + (nt * 16 + lm) * 128 + lg * 8;
        const short* Wl = (const short*)W2l + (nt * 16 + lm) * 128 + lg * 8;
#pragma unroll
        for (int kb = 0; kb < 4; ++kb) {
            short8 wh = *(const short8*)(Wh + kb * 32);
            short8 wl = *(const short8*)(Wl + kb * 32);
            acc2[nt] = __builtin_amdgcn_mfma_f32_16x16x32_bf16(hh[kb], wh, acc2[nt], 0, 0, 0);
            acc2[nt] = __builtin_amdgcn_mfma_f32_16x16x32_bf16(hl[kb], wh, acc2[nt], 0, 0, 0);
            acc2[nt] = __builtin_amdgcn_mfma_f32_16x16x32_bf16(hh[kb], wl, acc2[nt], 0, 0, 0);
        }
    }
#pragma unroll
    for (int nt = 0; nt < NT2; ++nt) {
        int col = nt * 16 + lm;
        float b = LOGITS ? (col < 40 ? B2[col] : 0.f) : B2[col];
#pragma unroll
        for (int r = 0; r < 4; ++r) {
            int row = r0 + w * 16 + lg * 4 + r;
            if (row < M) {
                float v = acc2[nt][r] + b;
                if (RELU_OUT) v = v > 0.f ? v : 0.f;
                if (LOGITS) {
                    if (col < 40) OutF[row * 40 + col] = v;
                } else {
                    OutF[row * 128 + col] = v;
                }
            }
        }
    }
}

// ---------------- log_softmax over 40 cols (fp32 in/out) ----------------
__global__ __launch_bounds__(256) void k_lsm(const float* __restrict__ logits,
                                             float* __restrict__ out, int M) {
    int wave = threadIdx.x >> 6, lane = threadIdx.x & 63;
    int row = blockIdx.x * 4 + wave;
    if (row >= M) return;
    float v = (lane < 40) ? logits[row * 40 + lane] : -1e30f;
    float m = v;
#pragma unroll
    for (int o = 32; o >= 1; o >>= 1) m = fmaxf(m, __shfl_xor(m, o, 64));
    float ex = (lane < 40) ? expf(v - m) : 0.f;
    float s = ex;
#pragma unroll
    for (int o = 32; o >= 1; o >>= 1) s += __shfl_xor(s, o, 64);
    float ls = logf(s);
    if (lane < 40) out[row * 40 + lane] = v - m - ls;
}

// ---------------- launch ----------------
extern "C" void kernel_launch(void* const* d_in, const int* in_sizes, int n_in,
                              void* d_out, int out_size, void* d_ws, size_t ws_size,
                              hipStream_t stream) {
    const float* x    = (const float*)d_in[0];
    const int*   edges = (const int*)d_in[1];
    const float* W1_0 = (const float*)d_in[2];
    const float* b1_0 = (const float*)d_in[3];
    const float* W2_0 = (const float*)d_in[4];
    const float* b2_0 = (const float*)d_in[5];
    const float* eps0 = (const float*)d_in[6];
    const float* W1_1 = (const float*)d_in[7];
    const float* b1_1 = (const float*)d_in[8];
    const float* W2_1 = (const float*)d_in[9];
    const float* b2_1 = (const float*)d_in[10];
    const float* eps1 = (const float*)d_in[11];
    const float* W1_2 = (const float*)d_in[12];
    const float* b1_2 = (const float*)d_in[13];
    const float* W2_2 = (const float*)d_in[14];
    const float* b2_2 = (const float*)d_in[15];
    const float* eps2 = (const float*)d_in[16];

    int M  = in_sizes[0] / 128;   // 100000
    int nE = in_sizes[1] / 2;     // 1600000
    const int* e_src = edges;
    const int* e_dst = edges + nE;

    char* ws = (char*)d_ws;
    size_t o = 0;
    auto alloc = [&](size_t bytes) {
        size_t p = o;
        o = (o + bytes + 511) & ~(size_t)511;
        return ws + p;
    };
    int* bucketCnt  = (int*)alloc(512 * 4);
    int* bucketBase = (int*)alloc(513 * 4);
    int* bucketCur  = (int*)alloc(512 * 4);
    int* off  = (int*)alloc((size_t)(M + 1) * 4);
    int* esrc = (int*)alloc((size_t)nE * 4);
    unsigned int* ebuf = (unsigned int*)alloc((size_t)nE * 4);
    unsigned short* w1h[3]; unsigned short* w1l[3];
    unsigned short* w2h[3]; unsigned short* w2l[3];
    for (int L = 0; L < 3; ++L) {
        w1h[L] = (unsigned short*)alloc(128 * 128 * 2);
        w1l[L] = (unsigned short*)alloc(128 * 128 * 2);
        int npad = (L == 2) ? 48 : 128;
        w2h[L] = (unsigned short*)alloc((size_t)npad * 128 * 2);
        w2l[L] = (unsigned short*)alloc((size_t)npad * 128 * 2);
    }
    float* HfA = (float*)alloc((size_t)M * 128 * 4);
    float* HfB = (float*)alloc((size_t)M * 128 * 4);
    float* logit = HfA;   // HfA dead when layer 2 runs (layer2 reads HfB)
    (void)ws_size; (void)n_in; (void)out_size;

    hipMemsetAsync(bucketCnt, 0, 512 * 4, stream);

    int nChunk = (nE + 4095) / 4096;          // 391
    int nBk = (M + 255) / 256;                // 391
    bs_count<<<nChunk, 256, 0, stream>>>(e_dst, nE, bucketCnt);
    bs_scan<<<1, 512, 0, stream>>>(bucketCnt, bucketBase, bucketCur, off, M, nE);
    bs_scatter<<<nChunk, 512, 0, stream>>>(e_src, e_dst, nE, bucketCur, ebuf);
    bs_build<<<nBk, 512, 0, stream>>>(ebuf, bucketBase, off, esrc, M);

    k_wprep<<<64, 256, 0, stream>>>(W1_0, w1h[0], w1l[0], 128, 128);
    k_wprep<<<64, 256, 0, stream>>>(W2_0, w2h[0], w2l[0], 128, 128);
    k_wprep<<<64, 256, 0, stream>>>(W1_1, w1h[1], w1l[1], 128, 128);
    k_wprep<<<64, 256, 0, stream>>>(W2_1, w2h[1], w2l[1], 128, 128);
    k_wprep<<<64, 256, 0, stream>>>(W1_2, w1h[2], w1l[2], 128, 128);
    k_wprep<<<24, 256, 0, stream>>>(W2_2, w2h[2], w2l[2], 40, 48);

    int gL = (M + 63) / 64;                   // 1563
    k_layer<8, true, false><<<gL, 256, 0, stream>>>(
        (const float2*)x, off, esrc, eps0,
        w1h[0], w1l[0], b1_0, w2h[0], w2l[0], b2_0, HfA, M);
    k_layer<8, true, false><<<gL, 256, 0, stream>>>(
        (const float2*)HfA, off, esrc, eps1,
        w1h[1], w1l[1], b1_1, w2h[1], w2l[1], b2_1, HfB, M);
    k_layer<3, false, true><<<gL, 256, 0, stream>>>(
        (const float2*)HfB, off, esrc, eps2,
        w1h[2], w1l[2], b1_2, w2h[2], w2l[2], b2_2, logit, M);
    k_lsm<<<(M + 3) / 4, 256, 0, stream>>>(logit, (float*)d_out, M);
}

// Round 4
// 817.284 us; speedup vs baseline: 1.2796x; 1.1655x over previous
//
#include <hip/hip_runtime.h>
#include <stdint.h>

typedef __attribute__((ext_vector_type(8))) short short8;
typedef __attribute__((ext_vector_type(4))) float float4v;

__device__ __forceinline__ float bf2f(unsigned short s) {
    union { unsigned int u; float f; } c; c.u = ((unsigned int)s) << 16; return c.f;
}
__device__ __forceinline__ unsigned short f2bf(float f) {
    union { float f; unsigned int u; } c; c.f = f;
    unsigned int x = c.u;
    unsigned int r = x + 0x7fffu + ((x >> 16) & 1u);   // RNE
    return (unsigned short)(r >> 16);
}

// ================= CSR build via bucket sort (bucket = dst>>8) =================
__global__ __launch_bounds__(256) void bs_count(const int* __restrict__ dst, int nE,
                                                int* __restrict__ bucketCnt) {
    __shared__ int c[512];
    int t = threadIdx.x;
    for (int i = t; i < 512; i += 256) c[i] = 0;
    __syncthreads();
    int base = blockIdx.x * 4096;
    for (int i = t; i < 4096; i += 256) {
        int e = base + i;
        if (e < nE) atomicAdd(&c[dst[e] >> 8], 1);
    }
    __syncthreads();
    for (int i = t; i < 512; i += 256)
        if (c[i]) atomicAdd(&bucketCnt[i], c[i]);
}

__global__ __launch_bounds__(512) void bs_scan(const int* __restrict__ bucketCnt,
                                               int* __restrict__ bucketBase,
                                               int* __restrict__ bucketCur,
                                               int* __restrict__ off, int M, int nE) {
    __shared__ int s[512];
    int t = threadIdx.x;
    int v = bucketCnt[t];
    s[t] = v;
    __syncthreads();
    for (int o = 1; o < 512; o <<= 1) {
        int x = (t >= o) ? s[t - o] : 0;
        __syncthreads();
        s[t] += x;
        __syncthreads();
    }
    bucketBase[t] = s[t] - v;
    bucketCur[t] = s[t] - v;
    if (t == 511) bucketBase[512] = s[511];
    if (t == 0) off[M] = nE;
}

// packed entry: src (bits 0..16) | (dst&255)<<17
__global__ __launch_bounds__(512) void bs_scatter(const int* __restrict__ src,
                                                  const int* __restrict__ dst, int nE,
                                                  int* __restrict__ bucketCur,
                                                  unsigned int* __restrict__ ebuf) {
    __shared__ int cnt[512];
    __shared__ int excl[512];
    __shared__ int chunk[512];
    __shared__ unsigned int buf[4096];
    __shared__ unsigned short bkt[4096];
    int t = threadIdx.x;
    cnt[t] = 0;
    __syncthreads();
    int base = blockIdx.x * 4096;
    int n = nE - base; if (n > 4096) n = 4096;
    unsigned int pk[8]; int bk[8]; int rk[8];
#pragma unroll
    for (int u = 0; u < 8; ++u) {
        int i = t + u * 512;
        if (i < n) {
            int e = base + i;
            int d = dst[e];
            int b = d >> 8;
            bk[u] = b;
            pk[u] = (unsigned int)src[e] | ((unsigned int)(d & 255) << 17);
            rk[u] = atomicAdd(&cnt[b], 1);
        } else bk[u] = -1;
    }
    __syncthreads();
    excl[t] = cnt[t];
    __syncthreads();
    for (int o = 1; o < 512; o <<= 1) {
        int x = (t >= o) ? excl[t - o] : 0;
        __syncthreads();
        excl[t] += x;
        __syncthreads();
    }
    int ex = excl[t] - cnt[t];
    __syncthreads();
    excl[t] = ex;
    if (cnt[t]) chunk[t] = atomicAdd(&bucketCur[t], cnt[t]);
    __syncthreads();
#pragma unroll
    for (int u = 0; u < 8; ++u) {
        if (bk[u] >= 0) {
            int lp = excl[bk[u]] + rk[u];
            buf[lp] = pk[u];
            bkt[lp] = (unsigned short)bk[u];
        }
    }
    __syncthreads();
    for (int i = t; i < n; i += 512) {
        int b = bkt[i];
        ebuf[chunk[b] + (i - excl[b])] = buf[i];
    }
}

__global__ __launch_bounds__(512) void bs_build(const unsigned int* __restrict__ ebuf,
                                                const int* __restrict__ bucketBase,
                                                int* __restrict__ off,
                                                int* __restrict__ esrc, int M) {
    __shared__ int cnt[256];
    __shared__ int excl[256];
    __shared__ int obuf[5120];
    int t = threadIdx.x, b = blockIdx.x;
    int base = bucketBase[b];
    int n = bucketBase[b + 1] - base;
    if (t < 256) cnt[t] = 0;
    __syncthreads();
    unsigned int pk[10]; int dl[10]; int rk[10];
#pragma unroll
    for (int u = 0; u < 10; ++u) {
        int i = t + u * 512;
        if (i < n) {
            unsigned int p = ebuf[base + i];
            pk[u] = p;
            int d = (p >> 17) & 255;
            dl[u] = d;
            rk[u] = atomicAdd(&cnt[d], 1);
        } else dl[u] = -1;
    }
    __syncthreads();
    if (t < 256) excl[t] = cnt[t];
    __syncthreads();
    for (int o = 1; o < 256; o <<= 1) {
        int x = (t < 256 && t >= o) ? excl[t - o] : 0;
        __syncthreads();
        if (t < 256) excl[t] += x;
        __syncthreads();
    }
    if (t < 256) {
        int ex = excl[t] - cnt[t];
        int node = b * 256 + t;
        if (node < M) off[node] = base + ex;
        excl[t] = ex;
    }
    __syncthreads();
#pragma unroll
    for (int u = 0; u < 10; ++u) {
        if (dl[u] >= 0) {
            int lp = excl[dl[u]] + rk[u];
            if (lp < 5120) obuf[lp] = (int)(pk[u] & 0x1FFFF);
        }
    }
    __syncthreads();
    for (int i = t; i < n; i += 512) esrc[base + i] = obuf[i];
}

// ============ weight prep: fp32 W[k][n] -> bf16 hi/lo transposed [n][k] ============
struct WPack {
    const float* W[6];
    unsigned short* hi[6];
    unsigned short* lo[6];
};

__global__ __launch_bounds__(256) void k_wprep_all(WPack p) {
    int b = blockIdx.x;
    int mat = b >> 6;                 // 0..4 = 64 blocks each, 5 = blocks 320..343
    int rel = b - mat * 64;
    int NPAD = (mat == 5) ? 48 : 128;
    int N = (mat == 5) ? 40 : 128;
    int idx = rel * 256 + threadIdx.x;
    if (idx >= NPAD * 128) return;
    int n = idx >> 7, k = idx & 127;
    float w = (n < N) ? p.W[mat][k * N + n] : 0.f;
    unsigned short h = f2bf(w);
    p.hi[mat][idx] = h;
    p.lo[mat][idx] = f2bf(w - bf2f(h));
}

// ======= aggregation: a = (1+eps)*h + sum_{j->i} h_j ; emit bf16 hi/lo planes ======
// One wave per node; lane halves process 2 neighbors per instruction (float4 rows).
__global__ __launch_bounds__(256) void k_aggr(const float4* __restrict__ Hin,
                                              const int* __restrict__ off,
                                              const int* __restrict__ esrc,
                                              const float* __restrict__ epsp,
                                              uint2* __restrict__ Ahi,
                                              uint2* __restrict__ Alo, int M) {
    int w = threadIdx.x >> 6, lane = threadIdx.x & 63;
    int li = lane & 31, half = lane >> 5;
    int node = blockIdx.x * 4 + w;
    if (node >= M) return;
    float ep = 1.0f + epsp[0];
    float4 own = Hin[node * 32 + li];
    float sx = 0.f, sy = 0.f, sz = 0.f, sw = 0.f;
    int i = off[node], e = off[node + 1];
    for (; i + 16 <= e; i += 16) {
        float4 v[8];
#pragma unroll
        for (int j = 0; j < 8; ++j) {
            int sj = esrc[i + 2 * j + half];
            v[j] = Hin[sj * 32 + li];
        }
#pragma unroll
        for (int j = 0; j < 8; ++j) {
            sx += v[j].x; sy += v[j].y; sz += v[j].z; sw += v[j].w;
        }
    }
    for (; i + 2 <= e; i += 2) {
        int sj = esrc[i + half];
        float4 v0 = Hin[sj * 32 + li];
        sx += v0.x; sy += v0.y; sz += v0.z; sw += v0.w;
    }
    if (i < e && half == 0) {
        float4 v0 = Hin[esrc[i] * 32 + li];
        sx += v0.x; sy += v0.y; sz += v0.z; sw += v0.w;
    }
    sx += __shfl_xor(sx, 32);
    sy += __shfl_xor(sy, 32);
    sz += __shfl_xor(sz, 32);
    sw += __shfl_xor(sw, 32);
    if (half == 0) {
        float r0 = ep * own.x + sx, r1 = ep * own.y + sy;
        float r2 = ep * own.z + sz, r3 = ep * own.w + sw;
        unsigned short h0 = f2bf(r0), h1 = f2bf(r1), h2 = f2bf(r2), h3 = f2bf(r3);
        uint2 hi, lo;
        hi.x = ((unsigned int)h1 << 16) | h0;
        hi.y = ((unsigned int)h3 << 16) | h2;
        lo.x = ((unsigned int)f2bf(r1 - bf2f(h1)) << 16) | f2bf(r0 - bf2f(h0));
        lo.y = ((unsigned int)f2bf(r3 - bf2f(h3)) << 16) | f2bf(r2 - bf2f(h2));
        Ahi[node * 32 + li] = hi;
        Alo[node * 32 + li] = lo;
    }
}

// ============== fused 2-layer MLP (bf16x3 MFMA), optional fused log_softmax ========
// A: bf16 hi/lo [M][128]. W*: bf16 hi/lo transposed [n][128] (L1-resident).
// !LOGITS: OutF = fp32 [M][128] (with relu). LOGITS: OutF = log_softmax fp32 [M][40].
template <int NT2, bool RELU, bool LOGITS>
__global__ __launch_bounds__(256) void k_mlp(const unsigned short* __restrict__ AhiS,
                                             const unsigned short* __restrict__ AloS,
                                             const unsigned short* __restrict__ W1h,
                                             const unsigned short* __restrict__ W1l,
                                             const float* __restrict__ B1,
                                             const unsigned short* __restrict__ W2h,
                                             const unsigned short* __restrict__ W2l,
                                             const float* __restrict__ B2,
                                             float* __restrict__ OutF, int M) {
    __shared__ short slab[4][16 * 136];   // wave-private; reused for hi then lo
    int t = threadIdx.x, w = t >> 6, lane = t & 63;
    int lm = lane & 15, lg = lane >> 4;
    int r0w = blockIdx.x * 64 + w * 16;
    if (r0w >= M) return;   // wave-uniform; M % 16 == 0

    // ---- GEMM1: H = relu(A @ W1 + b1) ----
    const short* Ah = (const short*)AhiS + (r0w + lm) * 128 + lg * 8;
    const short* Al = (const short*)AloS + (r0w + lm) * 128 + lg * 8;
    short8 ah[4], al[4];
#pragma unroll
    for (int kb = 0; kb < 4; ++kb) {
        ah[kb] = *(const short8*)(Ah + kb * 32);
        al[kb] = *(const short8*)(Al + kb * 32);
    }
    float4v acc[8];
#pragma unroll
    for (int nt = 0; nt < 8; ++nt) acc[nt] = (float4v){0.f, 0.f, 0.f, 0.f};
#pragma unroll
    for (int nt = 0; nt < 8; ++nt) {
        const short* Wh = (const short*)W1h + (nt * 16 + lm) * 128 + lg * 8;
        const short* Wl = (const short*)W1l + (nt * 16 + lm) * 128 + lg * 8;
#pragma unroll
        for (int kb = 0; kb < 4; ++kb) {
            short8 wh = *(const short8*)(Wh + kb * 32);
            short8 wl = *(const short8*)(Wl + kb * 32);
            acc[nt] = __builtin_amdgcn_mfma_f32_16x16x32_bf16(ah[kb], wh, acc[nt], 0, 0, 0);
            acc[nt] = __builtin_amdgcn_mfma_f32_16x16x32_bf16(al[kb], wh, acc[nt], 0, 0, 0);
            acc[nt] = __builtin_amdgcn_mfma_f32_16x16x32_bf16(ah[kb], wl, acc[nt], 0, 0, 0);
        }
    }
    // bias + relu; stash fp32 H in registers as hi part + residual via two slab passes
    float hv[8][4];
#pragma unroll
    for (int nt = 0; nt < 8; ++nt) {
        float b = B1[nt * 16 + lm];
#pragma unroll
        for (int r = 0; r < 4; ++r) {
            float v = acc[nt][r] + b;
            hv[nt][r] = v > 0.f ? v : 0.f;
        }
    }
    // pass 1: hi plane through slab -> hh frags
#pragma unroll
    for (int nt = 0; nt < 8; ++nt)
#pragma unroll
        for (int r = 0; r < 4; ++r)
            slab[w][(lg * 4 + r) * 136 + nt * 16 + lm] = (short)f2bf(hv[nt][r]);
    short8 hh[4];
#pragma unroll
    for (int kb = 0; kb < 4; ++kb)
        hh[kb] = *(const short8*)&slab[w][lm * 136 + kb * 32 + lg * 8];
    // pass 2: lo plane through the same slab -> hl frags (wave-private, in-order DS)
#pragma unroll
    for (int nt = 0; nt < 8; ++nt)
#pragma unroll
        for (int r = 0; r < 4; ++r) {
            float v = hv[nt][r];
            slab[w][(lg * 4 + r) * 136 + nt * 16 + lm] = (short)f2bf(v - bf2f(f2bf(v)));
        }
    short8 hl[4];
#pragma unroll
    for (int kb = 0; kb < 4; ++kb)
        hl[kb] = *(const short8*)&slab[w][lm * 136 + kb * 32 + lg * 8];

    // ---- GEMM2: Out = H @ W2 + b2 ----
    float4v acc2[NT2];
#pragma unroll
    for (int nt = 0; nt < NT2; ++nt) acc2[nt] = (float4v){0.f, 0.f, 0.f, 0.f};
#pragma unroll
    for (int nt = 0; nt < NT2; ++nt) {
        const short* Wh = (const short*)W2h + (nt * 16 + lm) * 128 + lg * 8;
        const short* Wl = (const short*)W2l + (nt * 16 + lm) * 128 + lg * 8;
#pragma unroll
        for (int kb = 0; kb < 4; ++kb) {
            short8 wh = *(const short8*)(Wh + kb * 32);
            short8 wl = *(const short8*)(Wl + kb * 32);
            acc2[nt] = __builtin_amdgcn_mfma_f32_16x16x32_bf16(hh[kb], wh, acc2[nt], 0, 0, 0);
            acc2[nt] = __builtin_amdgcn_mfma_f32_16x16x32_bf16(hl[kb], wh, acc2[nt], 0, 0, 0);
            acc2[nt] = __builtin_amdgcn_mfma_f32_16x16x32_bf16(hh[kb], wl, acc2[nt], 0, 0, 0);
        }
    }

    if (!LOGITS) {
#pragma unroll
        for (int nt = 0; nt < NT2; ++nt) {
            int col = nt * 16 + lm;
            float b = B2[col];
#pragma unroll
            for (int r = 0; r < 4; ++r) {
                float v = acc2[nt][r] + b;
                if (RELU) v = v > 0.f ? v : 0.f;
                OutF[(r0w + lg * 4 + r) * 128 + col] = v;
            }
        }
    } else {
        // fused log_softmax over 40 cols held by the 16-lane group (same lg)
        float vv[NT2][4];
#pragma unroll
        for (int nt = 0; nt < NT2; ++nt) {
            int col = nt * 16 + lm;
            bool valid = col < 40;
            float b = valid ? B2[col] : 0.f;
#pragma unroll
            for (int r = 0; r < 4; ++r)
                vv[nt][r] = valid ? (acc2[nt][r] + b) : -1e30f;
        }
#pragma unroll
        for (int r = 0; r < 4; ++r) {
            float m = vv[0][r];
#pragma unroll
            for (int nt = 1; nt < NT2; ++nt) m = fmaxf(m, vv[nt][r]);
#pragma unroll
            for (int o = 8; o >= 1; o >>= 1) m = fmaxf(m, __shfl_xor(m, o, 64));
            float s = 0.f;
#pragma unroll
            for (int nt = 0; nt < NT2; ++nt)
                s += (vv[nt][r] > -1e29f) ? expf(vv[nt][r] - m) : 0.f;
#pragma unroll
            for (int o = 8; o >= 1; o >>= 1) s += __shfl_xor(s, o, 64);
            float ls = m + logf(s);
            int row = r0w + lg * 4 + r;
#pragma unroll
            for (int nt = 0; nt < NT2; ++nt) {
                int col = nt * 16 + lm;
                if (col < 40) OutF[row * 40 + col] = vv[nt][r] - ls;
            }
        }
    }
}

// ---------------- launch ----------------
extern "C" void kernel_launch(void* const* d_in, const int* in_sizes, int n_in,
                              void* d_out, int out_size, void* d_ws, size_t ws_size,
                              hipStream_t stream) {
    const float* x    = (const float*)d_in[0];
    const int*   edges = (const int*)d_in[1];
    const float* eps0 = (const float*)d_in[6];
    const float* eps1 = (const float*)d_in[11];
    const float* eps2 = (const float*)d_in[16];
    const float* B1[3] = {(const float*)d_in[3], (const float*)d_in[8], (const float*)d_in[13]};
    const float* B2[3] = {(const float*)d_in[5], (const float*)d_in[10], (const float*)d_in[15]};

    int M  = in_sizes[0] / 128;   // 100000
    int nE = in_sizes[1] / 2;     // 1600000
    const int* e_src = edges;
    const int* e_dst = edges + nE;

    char* ws = (char*)d_ws;
    size_t o = 0;
    auto alloc = [&](size_t bytes) {
        size_t p = o;
        o = (o + bytes + 511) & ~(size_t)511;
        return ws + p;
    };
    int* bucketCnt  = (int*)alloc(512 * 4);
    int* bucketBase = (int*)alloc(513 * 4);
    int* bucketCur  = (int*)alloc(512 * 4);
    int* off  = (int*)alloc((size_t)(M + 1) * 4);
    int* esrc = (int*)alloc((size_t)nE * 4);
    unsigned int* ebuf = (unsigned int*)alloc((size_t)nE * 4);

    WPack wp;
    wp.W[0] = (const float*)d_in[2];  wp.W[1] = (const float*)d_in[4];
    wp.W[2] = (const float*)d_in[7];  wp.W[3] = (const float*)d_in[9];
    wp.W[4] = (const float*)d_in[12]; wp.W[5] = (const float*)d_in[14];
    for (int m = 0; m < 6; ++m) {
        int npad = (m == 5) ? 48 : 128;
        wp.hi[m] = (unsigned short*)alloc((size_t)npad * 128 * 2);
        wp.lo[m] = (unsigned short*)alloc((size_t)npad * 128 * 2);
    }
    unsigned short* Ahi = (unsigned short*)alloc((size_t)M * 128 * 2);
    unsigned short* Alo = (unsigned short*)alloc((size_t)M * 128 * 2);
    float* Hf = (float*)alloc((size_t)M * 128 * 4);
    (void)ws_size; (void)n_in; (void)out_size;

    hipMemsetAsync(bucketCnt, 0, 512 * 4, stream);
    int nChunk = (nE + 4095) / 4096;
    int nBk = (M + 255) / 256;
    bs_count<<<nChunk, 256, 0, stream>>>(e_dst, nE, bucketCnt);
    bs_scan<<<1, 512, 0, stream>>>(bucketCnt, bucketBase, bucketCur, off, M, nE);
    bs_scatter<<<nChunk, 512, 0, stream>>>(e_src, e_dst, nE, bucketCur, ebuf);
    bs_build<<<nBk, 512, 0, stream>>>(ebuf, bucketBase, off, esrc, M);
    k_wprep_all<<<344, 256, 0, stream>>>(wp);

    int gA = (M + 3) / 4;      // 25000
    int gG = (M + 63) / 64;    // 1563

    // layer 0
    k_aggr<<<gA, 256, 0, stream>>>((const float4*)x, off, esrc, eps0,
                                   (uint2*)Ahi, (uint2*)Alo, M);
    k_mlp<8, true, false><<<gG, 256, 0, stream>>>(Ahi, Alo, wp.hi[0], wp.lo[0], B1[0],
                                                  wp.hi[1], wp.lo[1], B2[0], Hf, M);
    // layer 1
    k_aggr<<<gA, 256, 0, stream>>>((const float4*)Hf, off, esrc, eps1,
                                   (uint2*)Ahi, (uint2*)Alo, M);
    k_mlp<8, true, false><<<gG, 256, 0, stream>>>(Ahi, Alo, wp.hi[2], wp.lo[2], B1[1],
                                                  wp.hi[3], wp.lo[3], B2[1], Hf, M);
    // layer 2 (log_softmax fused)
    k_aggr<<<gA, 256, 0, stream>>>((const float4*)Hf, off, esrc, eps2,
                                   (uint2*)Ahi, (uint2*)Alo, M);
    k_mlp<3, false, true><<<gG, 256, 0, stream>>>(Ahi, Alo, wp.hi[4], wp.lo[4], B1[2],
                                                  wp.hi[5], wp.lo[5], B2[2],
                                                  (float*)d_out, M);
}

// Round 5
// 466.497 us; speedup vs baseline: 2.2417x; 1.7520x over previous
//
#include <hip/hip_runtime.h>
#include <stdint.h>

typedef __attribute__((ext_vector_type(8))) short short8;
typedef __attribute__((ext_vector_type(4))) float float4v;

__device__ __forceinline__ float bf2f(unsigned short s) {
    union { unsigned int u; float f; } c; c.u = ((unsigned int)s) << 16; return c.f;
}
__device__ __forceinline__ unsigned short f2bf(float f) {
    union { float f; unsigned int u; } c; c.f = f;
    unsigned int x = c.u;
    unsigned int r = x + 0x7fffu + ((x >> 16) & 1u);   // RNE
    return (unsigned short)(r >> 16);
}
__device__ __forceinline__ void unpack2(unsigned int u, float& lo, float& hi) {
    union { unsigned int uu; float ff; } a, b;
    a.uu = u << 16;          // low bf16
    b.uu = u & 0xffff0000u;  // high bf16
    lo = a.ff; hi = b.ff;
}

// ================= CSR build via bucket sort (bucket = dst>>8) =================
__global__ __launch_bounds__(256) void bs_count(const int* __restrict__ dst, int nE,
                                                int* __restrict__ bucketCnt) {
    __shared__ int c[512];
    int t = threadIdx.x;
    for (int i = t; i < 512; i += 256) c[i] = 0;
    __syncthreads();
    int base = blockIdx.x * 4096;
    for (int i = t; i < 4096; i += 256) {
        int e = base + i;
        if (e < nE) atomicAdd(&c[dst[e] >> 8], 1);
    }
    __syncthreads();
    for (int i = t; i < 512; i += 256)
        if (c[i]) atomicAdd(&bucketCnt[i], c[i]);
}

__global__ __launch_bounds__(512) void bs_scan(const int* __restrict__ bucketCnt,
                                               int* __restrict__ bucketBase,
                                               int* __restrict__ bucketCur,
                                               int* __restrict__ off, int M, int nE) {
    __shared__ int s[512];
    int t = threadIdx.x;
    int v = bucketCnt[t];
    s[t] = v;
    __syncthreads();
    for (int o = 1; o < 512; o <<= 1) {
        int x = (t >= o) ? s[t - o] : 0;
        __syncthreads();
        s[t] += x;
        __syncthreads();
    }
    bucketBase[t] = s[t] - v;
    bucketCur[t] = s[t] - v;
    if (t == 511) bucketBase[512] = s[511];
    if (t == 0) off[M] = nE;
}

// packed entry: src (bits 0..16) | (dst&255)<<17
__global__ __launch_bounds__(512) void bs_scatter(const int* __restrict__ src,
                                                  const int* __restrict__ dst, int nE,
                                                  int* __restrict__ bucketCur,
                                                  unsigned int* __restrict__ ebuf) {
    __shared__ int cnt[512];
    __shared__ int excl[512];
    __shared__ int chunk[512];
    __shared__ unsigned int buf[4096];
    __shared__ unsigned short bkt[4096];
    int t = threadIdx.x;
    cnt[t] = 0;
    __syncthreads();
    int base = blockIdx.x * 4096;
    int n = nE - base; if (n > 4096) n = 4096;
    unsigned int pk[8]; int bk[8]; int rk[8];
#pragma unroll
    for (int u = 0; u < 8; ++u) {
        int i = t + u * 512;
        if (i < n) {
            int e = base + i;
            int d = dst[e];
            int b = d >> 8;
            bk[u] = b;
            pk[u] = (unsigned int)src[e] | ((unsigned int)(d & 255) << 17);
            rk[u] = atomicAdd(&cnt[b], 1);
        } else bk[u] = -1;
    }
    __syncthreads();
    excl[t] = cnt[t];
    __syncthreads();
    for (int o = 1; o < 512; o <<= 1) {
        int x = (t >= o) ? excl[t - o] : 0;
        __syncthreads();
        excl[t] += x;
        __syncthreads();
    }
    int ex = excl[t] - cnt[t];
    __syncthreads();
    excl[t] = ex;
    if (cnt[t]) chunk[t] = atomicAdd(&bucketCur[t], cnt[t]);
    __syncthreads();
#pragma unroll
    for (int u = 0; u < 8; ++u) {
        if (bk[u] >= 0) {
            int lp = excl[bk[u]] + rk[u];
            buf[lp] = pk[u];
            bkt[lp] = (unsigned short)bk[u];
        }
    }
    __syncthreads();
    for (int i = t; i < n; i += 512) {
        int b = bkt[i];
        ebuf[chunk[b] + (i - excl[b])] = buf[i];
    }
}

__global__ __launch_bounds__(512) void bs_build(const unsigned int* __restrict__ ebuf,
                                                const int* __restrict__ bucketBase,
                                                int* __restrict__ off,
                                                int* __restrict__ esrc, int M) {
    __shared__ int cnt[256];
    __shared__ int excl[256];
    __shared__ int obuf[5120];
    int t = threadIdx.x, b = blockIdx.x;
    int base = bucketBase[b];
    int n = bucketBase[b + 1] - base;
    if (t < 256) cnt[t] = 0;
    __syncthreads();
    unsigned int pk[10]; int dl[10]; int rk[10];
#pragma unroll
    for (int u = 0; u < 10; ++u) {
        int i = t + u * 512;
        if (i < n) {
            unsigned int p = ebuf[base + i];
            pk[u] = p;
            int d = (p >> 17) & 255;
            dl[u] = d;
            rk[u] = atomicAdd(&cnt[d], 1);
        } else dl[u] = -1;
    }
    __syncthreads();
    if (t < 256) excl[t] = cnt[t];
    __syncthreads();
    for (int o = 1; o < 256; o <<= 1) {
        int x = (t < 256 && t >= o) ? excl[t - o] : 0;
        __syncthreads();
        if (t < 256) excl[t] += x;
        __syncthreads();
    }
    if (t < 256) {
        int ex = excl[t] - cnt[t];
        int node = b * 256 + t;
        if (node < M) off[node] = base + ex;
        excl[t] = ex;
    }
    __syncthreads();
#pragma unroll
    for (int u = 0; u < 10; ++u) {
        if (dl[u] >= 0) {
            int lp = excl[dl[u]] + rk[u];
            if (lp < 5120) obuf[lp] = (int)(pk[u] & 0x1FFFF);
        }
    }
    __syncthreads();
    for (int i = t; i < n; i += 512) esrc[base + i] = obuf[i];
}

// ======== weight prep: fp32 W[k][n] -> bf16 (hi) transposed [n][k] ========
struct WPack {
    const float* W[6];
    unsigned short* hi[6];
};

__global__ __launch_bounds__(256) void k_wprep_all(WPack p) {
    int b = blockIdx.x;
    int mat = b >> 6;                 // mats 0..4: 64 blocks each; mat 5: blocks 320..343
    int rel = b - mat * 64;
    int NPAD = (mat == 5) ? 48 : 128;
    int N = (mat == 5) ? 40 : 128;
    int idx = rel * 256 + threadIdx.x;
    if (idx >= NPAD * 128) return;
    int n = idx >> 7, k = idx & 127;
    float w = (n < N) ? p.W[mat][k * N + n] : 0.f;
    p.hi[mat][idx] = f2bf(w);
}

// ======== cast x fp32 -> bf16 packed ========
__global__ __launch_bounds__(256) void k_cast(const float4* __restrict__ in,
                                              uint2* __restrict__ out, int n4) {
    int i = blockIdx.x * 256 + threadIdx.x;
    if (i >= n4) return;
    float4 v = in[i];
    uint2 o;
    o.x = ((unsigned int)f2bf(v.y) << 16) | f2bf(v.x);
    o.y = ((unsigned int)f2bf(v.w) << 16) | f2bf(v.z);
    out[i] = o;
}

// ======= aggregation: a = (1+eps)*h + sum_{j->i} h_j (h bf16) ; emit bf16 hi/lo ====
// One wave per node; rows are 256 B (128 bf16) = 32 uint2; lane halves do 2 nbrs/iter.
__global__ __launch_bounds__(256) void k_aggr(const uint2* __restrict__ Hin,
                                              const int* __restrict__ off,
                                              const int* __restrict__ esrc,
                                              const float* __restrict__ epsp,
                                              uint2* __restrict__ Ahi,
                                              uint2* __restrict__ Alo, int M) {
    int w = threadIdx.x >> 6, lane = threadIdx.x & 63;
    int li = lane & 31, half = lane >> 5;
    int node = blockIdx.x * 4 + w;
    if (node >= M) return;
    float ep = 1.0f + epsp[0];
    uint2 ow = Hin[node * 32 + li];
    float s0 = 0.f, s1 = 0.f, s2 = 0.f, s3 = 0.f;
    int i = off[node], e = off[node + 1];
    for (; i + 16 <= e; i += 16) {
        uint2 v[8];
#pragma unroll
        for (int j = 0; j < 8; ++j) v[j] = Hin[esrc[i + 2 * j + half] * 32 + li];
#pragma unroll
        for (int j = 0; j < 8; ++j) {
            float a, b, c, d;
            unpack2(v[j].x, a, b);
            unpack2(v[j].y, c, d);
            s0 += a; s1 += b; s2 += c; s3 += d;
        }
    }
    for (; i + 2 <= e; i += 2) {
        uint2 v = Hin[esrc[i + half] * 32 + li];
        float a, b, c, d;
        unpack2(v.x, a, b);
        unpack2(v.y, c, d);
        s0 += a; s1 += b; s2 += c; s3 += d;
    }
    if (i < e && half == 0) {
        uint2 v = Hin[esrc[i] * 32 + li];
        float a, b, c, d;
        unpack2(v.x, a, b);
        unpack2(v.y, c, d);
        s0 += a; s1 += b; s2 += c; s3 += d;
    }
    s0 += __shfl_xor(s0, 32);
    s1 += __shfl_xor(s1, 32);
    s2 += __shfl_xor(s2, 32);
    s3 += __shfl_xor(s3, 32);
    if (half == 0) {
        float o0, o1, o2, o3;
        unpack2(ow.x, o0, o1);
        unpack2(ow.y, o2, o3);
        float r0 = ep * o0 + s0, r1 = ep * o1 + s1;
        float r2 = ep * o2 + s2, r3 = ep * o3 + s3;
        unsigned short h0 = f2bf(r0), h1 = f2bf(r1), h2 = f2bf(r2), h3 = f2bf(r3);
        uint2 hi, lo;
        hi.x = ((unsigned int)h1 << 16) | h0;
        hi.y = ((unsigned int)h3 << 16) | h2;
        lo.x = ((unsigned int)f2bf(r1 - bf2f(h1)) << 16) | f2bf(r0 - bf2f(h0));
        lo.y = ((unsigned int)f2bf(r3 - bf2f(h3)) << 16) | f2bf(r2 - bf2f(h2));
        Ahi[node * 32 + li] = hi;
        Alo[node * 32 + li] = lo;
    }
}

// ============ fused 2-layer MLP, weights LDS-staged, 128 rows/block ============
// A as bf16 hi/lo planes [M][128]. W1h/W2h bf16 transposed [n][128] (hi plane only).
// GEMM1 = (ah+al)*wh (2-term); GEMM2 = hh*wh (1-term).
// !LOGITS: HOut = bf16 [M][128] with relu; LOGITS: LOut = fp32 log_softmax [M][40].
template <int NT2, bool LOGITS>
__global__ __launch_bounds__(256, 3) void k_mlp(const unsigned short* __restrict__ AhiS,
                                                const unsigned short* __restrict__ AloS,
                                                const unsigned short* __restrict__ W1h,
                                                const float* __restrict__ B1,
                                                const unsigned short* __restrict__ W2h,
                                                const float* __restrict__ B2,
                                                unsigned short* __restrict__ HOut,
                                                float* __restrict__ LOut, int M) {
    __shared__ short wbuf[128 * 136];     // 272 B row stride: b128-aligned, 2-way-free
    __shared__ short slab[4][16 * 136];   // wave-private transpose slab
    int t = threadIdx.x, w = t >> 6, lane = t & 63;
    int lm = lane & 15, lg = lane >> 4;
    int rbase = blockIdx.x * 128;

    // ---- stage W1h ----
    for (int i = t * 8; i < 128 * 128; i += 2048) {
        int n = i >> 7, k = i & 127;
        *(short8*)&wbuf[n * 136 + k] = *(const short8*)(W1h + i);
    }
    __syncthreads();

    short8 hh[2][4];
#pragma unroll
    for (int t2 = 0; t2 < 2; ++t2) {
        int r0 = rbase + t2 * 64 + w * 16;
        if (r0 < M) {   // wave-uniform
            const short* Ah = (const short*)AhiS + (r0 + lm) * 128 + lg * 8;
            const short* Al = (const short*)AloS + (r0 + lm) * 128 + lg * 8;
            short8 ah[4], al[4];
#pragma unroll
            for (int kb = 0; kb < 4; ++kb) {
                ah[kb] = *(const short8*)(Ah + kb * 32);
                al[kb] = *(const short8*)(Al + kb * 32);
            }
            float4v acc[8];
#pragma unroll
            for (int nt = 0; nt < 8; ++nt) acc[nt] = (float4v){0.f, 0.f, 0.f, 0.f};
#pragma unroll
            for (int nt = 0; nt < 8; ++nt) {
#pragma unroll
                for (int kb = 0; kb < 4; ++kb) {
                    short8 wh = *(const short8*)&wbuf[(nt * 16 + lm) * 136 + kb * 32 + lg * 8];
                    acc[nt] = __builtin_amdgcn_mfma_f32_16x16x32_bf16(ah[kb], wh, acc[nt], 0, 0, 0);
                    acc[nt] = __builtin_amdgcn_mfma_f32_16x16x32_bf16(al[kb], wh, acc[nt], 0, 0, 0);
                }
            }
            // bias + relu -> slab transpose (C-layout -> A-layout), bf16 hi only
#pragma unroll
            for (int nt = 0; nt < 8; ++nt) {
                float b = B1[nt * 16 + lm];
#pragma unroll
                for (int r = 0; r < 4; ++r) {
                    float v = acc[nt][r] + b;
                    v = v > 0.f ? v : 0.f;
                    slab[w][(lg * 4 + r) * 136 + nt * 16 + lm] = (short)f2bf(v);
                }
            }
#pragma unroll
            for (int kb = 0; kb < 4; ++kb)
                hh[t2][kb] = *(const short8*)&slab[w][lm * 136 + kb * 32 + lg * 8];
        }
    }

    __syncthreads();
    // ---- stage W2h over wbuf ----
    for (int i = t * 8; i < NT2 * 16 * 128; i += 2048) {
        int n = i >> 7, k = i & 127;
        *(short8*)&wbuf[n * 136 + k] = *(const short8*)(W2h + i);
    }
    __syncthreads();

#pragma unroll
    for (int t2 = 0; t2 < 2; ++t2) {
        int r0 = rbase + t2 * 64 + w * 16;
        if (r0 >= M) continue;   // wave-uniform, no barriers below
        float4v acc2[NT2];
#pragma unroll
        for (int nt = 0; nt < NT2; ++nt) acc2[nt] = (float4v){0.f, 0.f, 0.f, 0.f};
#pragma unroll
        for (int nt = 0; nt < NT2; ++nt) {
#pragma unroll
            for (int kb = 0; kb < 4; ++kb) {
                short8 wh = *(const short8*)&wbuf[(nt * 16 + lm) * 136 + kb * 32 + lg * 8];
                acc2[nt] = __builtin_amdgcn_mfma_f32_16x16x32_bf16(hh[t2][kb], wh, acc2[nt], 0, 0, 0);
            }
        }
        if (!LOGITS) {
#pragma unroll
            for (int nt = 0; nt < NT2; ++nt) {
                int col = nt * 16 + lm;
                float b = B2[col];
#pragma unroll
                for (int r = 0; r < 4; ++r) {
                    float v = acc2[nt][r] + b;
                    v = v > 0.f ? v : 0.f;
                    HOut[(r0 + lg * 4 + r) * 128 + col] = f2bf(v);
                }
            }
        } else {
            float vv[NT2][4];
#pragma unroll
            for (int nt = 0; nt < NT2; ++nt) {
                int col = nt * 16 + lm;
                bool valid = col < 40;
                float b = valid ? B2[col] : 0.f;
#pragma unroll
                for (int r = 0; r < 4; ++r)
                    vv[nt][r] = valid ? (acc2[nt][r] + b) : -1e30f;
            }
#pragma unroll
            for (int r = 0; r < 4; ++r) {
                float m = vv[0][r];
#pragma unroll
                for (int nt = 1; nt < NT2; ++nt) m = fmaxf(m, vv[nt][r]);
#pragma unroll
                for (int o = 8; o >= 1; o >>= 1) m = fmaxf(m, __shfl_xor(m, o, 64));
                float s = 0.f;
#pragma unroll
                for (int nt = 0; nt < NT2; ++nt)
                    s += (vv[nt][r] > -1e29f) ? expf(vv[nt][r] - m) : 0.f;
#pragma unroll
                for (int o = 8; o >= 1; o >>= 1) s += __shfl_xor(s, o, 64);
                float ls = m + logf(s);
                int row = r0 + lg * 4 + r;
#pragma unroll
                for (int nt = 0; nt < NT2; ++nt) {
                    int col = nt * 16 + lm;
                    if (col < 40) LOut[row * 40 + col] = vv[nt][r] - ls;
                }
            }
        }
    }
}

// ---------------- launch ----------------
extern "C" void kernel_launch(void* const* d_in, const int* in_sizes, int n_in,
                              void* d_out, int out_size, void* d_ws, size_t ws_size,
                              hipStream_t stream) {
    const float* x    = (const float*)d_in[0];
    const int*   edges = (const int*)d_in[1];
    const float* eps0 = (const float*)d_in[6];
    const float* eps1 = (const float*)d_in[11];
    const float* eps2 = (const float*)d_in[16];
    const float* B1[3] = {(const float*)d_in[3], (const float*)d_in[8], (const float*)d_in[13]};
    const float* B2[3] = {(const float*)d_in[5], (const float*)d_in[10], (const float*)d_in[15]};

    int M  = in_sizes[0] / 128;   // 100000
    int nE = in_sizes[1] / 2;     // 1600000
    const int* e_src = edges;
    const int* e_dst = edges + nE;

    char* ws = (char*)d_ws;
    size_t o = 0;
    auto alloc = [&](size_t bytes) {
        size_t p = o;
        o = (o + bytes + 511) & ~(size_t)511;
        return ws + p;
    };
    int* bucketCnt  = (int*)alloc(512 * 4);
    int* bucketBase = (int*)alloc(513 * 4);
    int* bucketCur  = (int*)alloc(512 * 4);
    int* off  = (int*)alloc((size_t)(M + 1) * 4);
    int* esrc = (int*)alloc((size_t)nE * 4);
    unsigned int* ebuf = (unsigned int*)alloc((size_t)nE * 4);

    WPack wp;
    wp.W[0] = (const float*)d_in[2];  wp.W[1] = (const float*)d_in[4];
    wp.W[2] = (const float*)d_in[7];  wp.W[3] = (const float*)d_in[9];
    wp.W[4] = (const float*)d_in[12]; wp.W[5] = (const float*)d_in[14];
    for (int m = 0; m < 6; ++m) {
        int npad = (m == 5) ? 48 : 128;
        wp.hi[m] = (unsigned short*)alloc((size_t)npad * 128 * 2);
    }
    unsigned short* xb  = (unsigned short*)alloc((size_t)M * 128 * 2);
    unsigned short* Ahi = (unsigned short*)alloc((size_t)M * 128 * 2);
    unsigned short* Alo = (unsigned short*)alloc((size_t)M * 128 * 2);
    unsigned short* Hb  = (unsigned short*)alloc((size_t)M * 128 * 2);
    (void)ws_size; (void)n_in; (void)out_size;

    hipMemsetAsync(bucketCnt, 0, 512 * 4, stream);
    int nChunk = (nE + 4095) / 4096;
    int nBk = (M + 255) / 256;
    bs_count<<<nChunk, 256, 0, stream>>>(e_dst, nE, bucketCnt);
    bs_scan<<<1, 512, 0, stream>>>(bucketCnt, bucketBase, bucketCur, off, M, nE);
    bs_scatter<<<nChunk, 512, 0, stream>>>(e_src, e_dst, nE, bucketCur, ebuf);
    bs_build<<<nBk, 512, 0, stream>>>(ebuf, bucketBase, off, esrc, M);
    k_wprep_all<<<344, 256, 0, stream>>>(wp);
    int n4 = M * 32;   // M*128/4
    k_cast<<<(n4 + 255) / 256, 256, 0, stream>>>((const float4*)x, (uint2*)xb, n4);

    int gA = (M + 3) / 4;        // 25000
    int gG = (M + 127) / 128;    // 782

    // layer 0
    k_aggr<<<gA, 256, 0, stream>>>((const uint2*)xb, off, esrc, eps0,
                                   (uint2*)Ahi, (uint2*)Alo, M);
    k_mlp<8, false><<<gG, 256, 0, stream>>>(Ahi, Alo, wp.hi[0], B1[0],
                                            wp.hi[1], B2[0], Hb, nullptr, M);
    // layer 1
    k_aggr<<<gA, 256, 0, stream>>>((const uint2*)Hb, off, esrc, eps1,
                                   (uint2*)Ahi, (uint2*)Alo, M);
    k_mlp<8, false><<<gG, 256, 0, stream>>>(Ahi, Alo, wp.hi[2], B1[1],
                                            wp.hi[3], B2[1], Hb, nullptr, M);
    // layer 2 (log_softmax fused)
    k_aggr<<<gA, 256, 0, stream>>>((const uint2*)Hb, off, esrc, eps2,
                                   (uint2*)Ahi, (uint2*)Alo, M);
    k_mlp<3, true><<<gG, 256, 0, stream>>>(Ahi, Alo, wp.hi[4], B1[2],
                                           wp.hi[5], B2[2], nullptr,
                                           (float*)d_out, M);
}

// Round 6
// 410.037 us; speedup vs baseline: 2.5504x; 1.1377x over previous
//
#include <hip/hip_runtime.h>
#include <stdint.h>

typedef __attribute__((ext_vector_type(8))) short short8;
typedef __attribute__((ext_vector_type(4))) float float4v;

__device__ __forceinline__ float bf2f(unsigned short s) {
    union { unsigned int u; float f; } c; c.u = ((unsigned int)s) << 16; return c.f;
}
__device__ __forceinline__ unsigned short f2bf(float f) {
    union { float f; unsigned int u; } c; c.f = f;
    unsigned int x = c.u;
    unsigned int r = x + 0x7fffu + ((x >> 16) & 1u);   // RNE
    return (unsigned short)(r >> 16);
}
__device__ __forceinline__ void unpack2(unsigned int u, float& lo, float& hi) {
    union { unsigned int uu; float ff; } a, b;
    a.uu = u << 16;          // low bf16
    b.uu = u & 0xffff0000u;  // high bf16
    lo = a.ff; hi = b.ff;
}

// ================= CSR build via bucket sort (bucket = dst>>8) =================
__global__ __launch_bounds__(256) void bs_count(const int* __restrict__ dst, int nE,
                                                int* __restrict__ bucketCnt) {
    __shared__ int c[512];
    int t = threadIdx.x;
    for (int i = t; i < 512; i += 256) c[i] = 0;
    __syncthreads();
    int base = blockIdx.x * 4096;
    for (int i = t; i < 4096; i += 256) {
        int e = base + i;
        if (e < nE) atomicAdd(&c[dst[e] >> 8], 1);
    }
    __syncthreads();
    for (int i = t; i < 512; i += 256)
        if (c[i]) atomicAdd(&bucketCnt[i], c[i]);
}

__global__ __launch_bounds__(512) void bs_scan(const int* __restrict__ bucketCnt,
                                               int* __restrict__ bucketBase,
                                               int* __restrict__ bucketCur,
                                               int* __restrict__ off, int M, int nE) {
    __shared__ int s[512];
    int t = threadIdx.x;
    int v = bucketCnt[t];
    s[t] = v;
    __syncthreads();
    for (int o = 1; o < 512; o <<= 1) {
        int x = (t >= o) ? s[t - o] : 0;
        __syncthreads();
        s[t] += x;
        __syncthreads();
    }
    bucketBase[t] = s[t] - v;
    bucketCur[t] = s[t] - v;
    if (t == 511) bucketBase[512] = s[511];
    if (t == 0) off[M] = nE;
}

// packed entry: src (bits 0..16) | (dst&255)<<17
__global__ __launch_bounds__(512) void bs_scatter(const int* __restrict__ src,
                                                  const int* __restrict__ dst, int nE,
                                                  int* __restrict__ bucketCur,
                                                  unsigned int* __restrict__ ebuf) {
    __shared__ int cnt[512];
    __shared__ int excl[512];
    __shared__ int chunk[512];
    __shared__ unsigned int buf[4096];
    __shared__ unsigned short bkt[4096];
    int t = threadIdx.x;
    cnt[t] = 0;
    __syncthreads();
    int base = blockIdx.x * 4096;
    int n = nE - base; if (n > 4096) n = 4096;
    unsigned int pk[8]; int bk[8]; int rk[8];
#pragma unroll
    for (int u = 0; u < 8; ++u) {
        int i = t + u * 512;
        if (i < n) {
            int e = base + i;
            int d = dst[e];
            int b = d >> 8;
            bk[u] = b;
            pk[u] = (unsigned int)src[e] | ((unsigned int)(d & 255) << 17);
            rk[u] = atomicAdd(&cnt[b], 1);
        } else bk[u] = -1;
    }
    __syncthreads();
    excl[t] = cnt[t];
    __syncthreads();
    for (int o = 1; o < 512; o <<= 1) {
        int x = (t >= o) ? excl[t - o] : 0;
        __syncthreads();
        excl[t] += x;
        __syncthreads();
    }
    int ex = excl[t] - cnt[t];
    __syncthreads();
    excl[t] = ex;
    if (cnt[t]) chunk[t] = atomicAdd(&bucketCur[t], cnt[t]);
    __syncthreads();
#pragma unroll
    for (int u = 0; u < 8; ++u) {
        if (bk[u] >= 0) {
            int lp = excl[bk[u]] + rk[u];
            buf[lp] = pk[u];
            bkt[lp] = (unsigned short)bk[u];
        }
    }
    __syncthreads();
    for (int i = t; i < n; i += 512) {
        int b = bkt[i];
        ebuf[chunk[b] + (i - excl[b])] = buf[i];
    }
}

__global__ __launch_bounds__(512) void bs_build(const unsigned int* __restrict__ ebuf,
                                                const int* __restrict__ bucketBase,
                                                int* __restrict__ off,
                                                int* __restrict__ esrc, int M) {
    __shared__ int cnt[256];
    __shared__ int excl[256];
    __shared__ int obuf[5120];
    int t = threadIdx.x, b = blockIdx.x;
    int base = bucketBase[b];
    int n = bucketBase[b + 1] - base;
    if (t < 256) cnt[t] = 0;
    __syncthreads();
    unsigned int pk[10]; int dl[10]; int rk[10];
#pragma unroll
    for (int u = 0; u < 10; ++u) {
        int i = t + u * 512;
        if (i < n) {
            unsigned int p = ebuf[base + i];
            pk[u] = p;
            int d = (p >> 17) & 255;
            dl[u] = d;
            rk[u] = atomicAdd(&cnt[d], 1);
        } else dl[u] = -1;
    }
    __syncthreads();
    if (t < 256) excl[t] = cnt[t];
    __syncthreads();
    for (int o = 1; o < 256; o <<= 1) {
        int x = (t < 256 && t >= o) ? excl[t - o] : 0;
        __syncthreads();
        if (t < 256) excl[t] += x;
        __syncthreads();
    }
    if (t < 256) {
        int ex = excl[t] - cnt[t];
        int node = b * 256 + t;
        if (node < M) off[node] = base + ex;
        excl[t] = ex;
    }
    __syncthreads();
#pragma unroll
    for (int u = 0; u < 10; ++u) {
        if (dl[u] >= 0) {
            int lp = excl[dl[u]] + rk[u];
            if (lp < 5120) obuf[lp] = (int)(pk[u] & 0x1FFFF);
        }
    }
    __syncthreads();
    for (int i = t; i < n; i += 512) esrc[base + i] = obuf[i];
}

// ======== weight prep: fp32 W[k][n] -> bf16 transposed [n][k] ========
struct WPack {
    const float* W[6];
    unsigned short* hi[6];
};

__global__ __launch_bounds__(256) void k_wprep_all(WPack p) {
    int b = blockIdx.x;
    int mat = b >> 6;                 // mats 0..4: 64 blocks each; mat 5: blocks 320..343
    int rel = b - mat * 64;
    int NPAD = (mat == 5) ? 48 : 128;
    int N = (mat == 5) ? 40 : 128;
    int idx = rel * 256 + threadIdx.x;
    if (idx >= NPAD * 128) return;
    int n = idx >> 7, k = idx & 127;
    float w = (n < N) ? p.W[mat][k * N + n] : 0.f;
    p.hi[mat][idx] = f2bf(w);
}

// ======== cast x fp32 -> bf16 packed ========
__global__ __launch_bounds__(256) void k_cast(const float4* __restrict__ in,
                                              uint2* __restrict__ out, int n4) {
    int i = blockIdx.x * 256 + threadIdx.x;
    if (i >= n4) return;
    float4 v = in[i];
    uint2 o;
    o.x = ((unsigned int)f2bf(v.y) << 16) | f2bf(v.x);
    o.y = ((unsigned int)f2bf(v.w) << 16) | f2bf(v.z);
    out[i] = o;
}

// ======= aggregation: a = (1+eps)*h + sum_{j->i} h_j (h bf16) ; emit bf16 =======
// One node per 32-lane half (2 nodes/wave). 8-deep predicated batches keep 8 row
// loads in flight always; tail duplicates clamp to the last edge (L1 hits) and are
// masked to zero before accumulation.
__global__ __launch_bounds__(256) void k_aggr(const uint2* __restrict__ Hin,
                                              const int* __restrict__ off,
                                              const int* __restrict__ esrc,
                                              const float* __restrict__ epsp,
                                              uint2* __restrict__ Ahi, int M) {
    int w = threadIdx.x >> 6, lane = threadIdx.x & 63;
    int li = lane & 31, half = lane >> 5;
    int node = blockIdx.x * 8 + w * 2 + half;
    if (node >= M) return;
    float ep = 1.0f + epsp[0];
    uint2 ow = Hin[node * 32 + li];
    float s0 = 0.f, s1 = 0.f, s2 = 0.f, s3 = 0.f;
    int i = off[node], e = off[node + 1];
    int last = e - 1;
    for (; i < e; i += 8) {
        uint2 v[8];
#pragma unroll
        for (int j = 0; j < 8; ++j) {
            int idx = i + j;
            int cl = idx < last ? idx : last;
            v[j] = Hin[esrc[cl] * 32 + li];
        }
#pragma unroll
        for (int j = 0; j < 8; ++j) {
            unsigned int ux = (i + j < e) ? v[j].x : 0u;
            unsigned int uy = (i + j < e) ? v[j].y : 0u;
            float a, b, c, d;
            unpack2(ux, a, b);
            unpack2(uy, c, d);
            s0 += a; s1 += b; s2 += c; s3 += d;
        }
    }
    float o0, o1, o2, o3;
    unpack2(ow.x, o0, o1);
    unpack2(ow.y, o2, o3);
    float r0 = ep * o0 + s0, r1 = ep * o1 + s1;
    float r2 = ep * o2 + s2, r3 = ep * o3 + s3;
    uint2 hi;
    hi.x = ((unsigned int)f2bf(r1) << 16) | f2bf(r0);
    hi.y = ((unsigned int)f2bf(r3) << 16) | f2bf(r2);
    Ahi[node * 32 + li] = hi;
}

// ============ fused 2-layer MLP, weights LDS-staged, 128 rows/block ============
// A bf16 [M][128]; W1h/W2h bf16 transposed [n][128].
// !LOGITS: HOut = bf16 [M][128] with relu; LOGITS: LOut = fp32 log_softmax [M][40].
template <int NT2, bool LOGITS>
__global__ __launch_bounds__(256, 3) void k_mlp(const unsigned short* __restrict__ AhiS,
                                                const unsigned short* __restrict__ W1h,
                                                const float* __restrict__ B1,
                                                const unsigned short* __restrict__ W2h,
                                                const float* __restrict__ B2,
                                                unsigned short* __restrict__ HOut,
                                                float* __restrict__ LOut, int M) {
    __shared__ short wbuf[128 * 136];     // 272 B row stride: b128-aligned, 2-way-free
    __shared__ short slab[4][16 * 136];   // wave-private transpose slab
    int t = threadIdx.x, w = t >> 6, lane = t & 63;
    int lm = lane & 15, lg = lane >> 4;
    int rbase = blockIdx.x * 128;

    // ---- stage W1h ----
    for (int i = t * 8; i < 128 * 128; i += 2048) {
        int n = i >> 7, k = i & 127;
        *(short8*)&wbuf[n * 136 + k] = *(const short8*)(W1h + i);
    }
    __syncthreads();

    short8 hh[2][4];
#pragma unroll
    for (int t2 = 0; t2 < 2; ++t2) {
        int r0 = rbase + t2 * 64 + w * 16;
        if (r0 < M) {   // wave-uniform
            const short* Ah = (const short*)AhiS + (r0 + lm) * 128 + lg * 8;
            short8 ah[4];
#pragma unroll
            for (int kb = 0; kb < 4; ++kb) ah[kb] = *(const short8*)(Ah + kb * 32);
            float4v acc[8];
#pragma unroll
            for (int nt = 0; nt < 8; ++nt) acc[nt] = (float4v){0.f, 0.f, 0.f, 0.f};
#pragma unroll
            for (int nt = 0; nt < 8; ++nt) {
#pragma unroll
                for (int kb = 0; kb < 4; ++kb) {
                    short8 wh = *(const short8*)&wbuf[(nt * 16 + lm) * 136 + kb * 32 + lg * 8];
                    acc[nt] = __builtin_amdgcn_mfma_f32_16x16x32_bf16(ah[kb], wh, acc[nt], 0, 0, 0);
                }
            }
            // bias + relu -> slab transpose (C-layout -> A-layout), bf16
#pragma unroll
            for (int nt = 0; nt < 8; ++nt) {
                float b = B1[nt * 16 + lm];
#pragma unroll
                for (int r = 0; r < 4; ++r) {
                    float v = acc[nt][r] + b;
                    v = v > 0.f ? v : 0.f;
                    slab[w][(lg * 4 + r) * 136 + nt * 16 + lm] = (short)f2bf(v);
                }
            }
#pragma unroll
            for (int kb = 0; kb < 4; ++kb)
                hh[t2][kb] = *(const short8*)&slab[w][lm * 136 + kb * 32 + lg * 8];
        }
    }

    __syncthreads();
    // ---- stage W2h over wbuf ----
    for (int i = t * 8; i < NT2 * 16 * 128; i += 2048) {
        int n = i >> 7, k = i & 127;
        *(short8*)&wbuf[n * 136 + k] = *(const short8*)(W2h + i);
    }
    __syncthreads();

#pragma unroll
    for (int t2 = 0; t2 < 2; ++t2) {
        int r0 = rbase + t2 * 64 + w * 16;
        if (r0 >= M) continue;   // wave-uniform, no barriers below
        float4v acc2[NT2];
#pragma unroll
        for (int nt = 0; nt < NT2; ++nt) acc2[nt] = (float4v){0.f, 0.f, 0.f, 0.f};
#pragma unroll
        for (int nt = 0; nt < NT2; ++nt) {
#pragma unroll
            for (int kb = 0; kb < 4; ++kb) {
                short8 wh = *(const short8*)&wbuf[(nt * 16 + lm) * 136 + kb * 32 + lg * 8];
                acc2[nt] = __builtin_amdgcn_mfma_f32_16x16x32_bf16(hh[t2][kb], wh, acc2[nt], 0, 0, 0);
            }
        }
        if (!LOGITS) {
#pragma unroll
            for (int nt = 0; nt < NT2; ++nt) {
                int col = nt * 16 + lm;
                float b = B2[col];
#pragma unroll
                for (int r = 0; r < 4; ++r) {
                    float v = acc2[nt][r] + b;
                    v = v > 0.f ? v : 0.f;
                    HOut[(r0 + lg * 4 + r) * 128 + col] = f2bf(v);
                }
            }
        } else {
            float vv[NT2][4];
#pragma unroll
            for (int nt = 0; nt < NT2; ++nt) {
                int col = nt * 16 + lm;
                bool valid = col < 40;
                float b = valid ? B2[col] : 0.f;
#pragma unroll
                for (int r = 0; r < 4; ++r)
                    vv[nt][r] = valid ? (acc2[nt][r] + b) : -1e30f;
            }
#pragma unroll
            for (int r = 0; r < 4; ++r) {
                float m = vv[0][r];
#pragma unroll
                for (int nt = 1; nt < NT2; ++nt) m = fmaxf(m, vv[nt][r]);
#pragma unroll
                for (int o = 8; o >= 1; o >>= 1) m = fmaxf(m, __shfl_xor(m, o, 64));
                float s = 0.f;
#pragma unroll
                for (int nt = 0; nt < NT2; ++nt)
                    s += (vv[nt][r] > -1e29f) ? expf(vv[nt][r] - m) : 0.f;
#pragma unroll
                for (int o = 8; o >= 1; o >>= 1) s += __shfl_xor(s, o, 64);
                float ls = m + logf(s);
                int row = r0 + lg * 4 + r;
#pragma unroll
                for (int nt = 0; nt < NT2; ++nt) {
                    int col = nt * 16 + lm;
                    if (col < 40) LOut[row * 40 + col] = vv[nt][r] - ls;
                }
            }
        }
    }
}

// ---------------- launch ----------------
extern "C" void kernel_launch(void* const* d_in, const int* in_sizes, int n_in,
                              void* d_out, int out_size, void* d_ws, size_t ws_size,
                              hipStream_t stream) {
    const float* x    = (const float*)d_in[0];
    const int*   edges = (const int*)d_in[1];
    const float* eps0 = (const float*)d_in[6];
    const float* eps1 = (const float*)d_in[11];
    const float* eps2 = (const float*)d_in[16];
    const float* B1[3] = {(const float*)d_in[3], (const float*)d_in[8], (const float*)d_in[13]};
    const float* B2[3] = {(const float*)d_in[5], (const float*)d_in[10], (const float*)d_in[15]};

    int M  = in_sizes[0] / 128;   // 100000
    int nE = in_sizes[1] / 2;     // 1600000
    const int* e_src = edges;
    const int* e_dst = edges + nE;

    char* ws = (char*)d_ws;
    size_t o = 0;
    auto alloc = [&](size_t bytes) {
        size_t p = o;
        o = (o + bytes + 511) & ~(size_t)511;
        return ws + p;
    };
    int* bucketCnt  = (int*)alloc(512 * 4);
    int* bucketBase = (int*)alloc(513 * 4);
    int* bucketCur  = (int*)alloc(512 * 4);
    int* off  = (int*)alloc((size_t)(M + 1) * 4);
    int* esrc = (int*)alloc((size_t)nE * 4);
    unsigned int* ebuf = (unsigned int*)alloc((size_t)nE * 4);

    WPack wp;
    wp.W[0] = (const float*)d_in[2];  wp.W[1] = (const float*)d_in[4];
    wp.W[2] = (const float*)d_in[7];  wp.W[3] = (const float*)d_in[9];
    wp.W[4] = (const float*)d_in[12]; wp.W[5] = (const float*)d_in[14];
    for (int m = 0; m < 6; ++m) {
        int npad = (m == 5) ? 48 : 128;
        wp.hi[m] = (unsigned short*)alloc((size_t)npad * 128 * 2);
    }
    unsigned short* xb  = (unsigned short*)alloc((size_t)M * 128 * 2);
    unsigned short* Ahi = (unsigned short*)alloc((size_t)M * 128 * 2);
    unsigned short* Hb  = (unsigned short*)alloc((size_t)M * 128 * 2);
    (void)ws_size; (void)n_in; (void)out_size;

    hipMemsetAsync(bucketCnt, 0, 512 * 4, stream);
    int nChunk = (nE + 4095) / 4096;
    int nBk = (M + 255) / 256;
    bs_count<<<nChunk, 256, 0, stream>>>(e_dst, nE, bucketCnt);
    bs_scan<<<1, 512, 0, stream>>>(bucketCnt, bucketBase, bucketCur, off, M, nE);
    bs_scatter<<<nChunk, 512, 0, stream>>>(e_src, e_dst, nE, bucketCur, ebuf);
    bs_build<<<nBk, 512, 0, stream>>>(ebuf, bucketBase, off, esrc, M);
    k_wprep_all<<<344, 256, 0, stream>>>(wp);
    int n4 = M * 32;   // M*128/4
    k_cast<<<(n4 + 255) / 256, 256, 0, stream>>>((const float4*)x, (uint2*)xb, n4);

    int gA = (M + 7) / 8;        // 12500
    int gG = (M + 127) / 128;    // 782

    // layer 0
    k_aggr<<<gA, 256, 0, stream>>>((const uint2*)xb, off, esrc, eps0, (uint2*)Ahi, M);
    k_mlp<8, false><<<gG, 256, 0, stream>>>(Ahi, wp.hi[0], B1[0],
                                            wp.hi[1], B2[0], Hb, nullptr, M);
    // layer 1
    k_aggr<<<gA, 256, 0, stream>>>((const uint2*)Hb, off, esrc, eps1, (uint2*)Ahi, M);
    k_mlp<8, false><<<gG, 256, 0, stream>>>(Ahi, wp.hi[2], B1[1],
                                            wp.hi[3], B2[1], Hb, nullptr, M);
    // layer 2 (log_softmax fused)
    k_aggr<<<gA, 256, 0, stream>>>((const uint2*)Hb, off, esrc, eps2, (uint2*)Ahi, M);
    k_mlp<3, true><<<gG, 256, 0, stream>>>(Ahi, wp.hi[4], B1[2],
                                           wp.hi[5], B2[2], nullptr,
                                           (float*)d_out, M);
}

// Round 7
// 408.387 us; speedup vs baseline: 2.5607x; 1.0040x over previous
//
#include <hip/hip_runtime.h>
#include <stdint.h>

typedef __attribute__((ext_vector_type(8))) short short8;
typedef __attribute__((ext_vector_type(4))) float float4v;

__device__ __forceinline__ float bf2f(unsigned short s) {
    union { unsigned int u; float f; } c; c.u = ((unsigned int)s) << 16; return c.f;
}
__device__ __forceinline__ unsigned short f2bf(float f) {
    union { float f; unsigned int u; } c; c.f = f;
    unsigned int x = c.u;
    unsigned int r = x + 0x7fffu + ((x >> 16) & 1u);   // RNE
    return (unsigned short)(r >> 16);
}
__device__ __forceinline__ void unpack2(unsigned int u, float& lo, float& hi) {
    union { unsigned int uu; float ff; } a, b;
    a.uu = u << 16;          // low bf16
    b.uu = u & 0xffff0000u;  // high bf16
    lo = a.ff; hi = b.ff;
}

// ================= CSR build via bucket sort (bucket = dst>>8) =================
__global__ __launch_bounds__(256) void bs_count(const int* __restrict__ dst, int nE,
                                                int* __restrict__ bucketCnt) {
    __shared__ int c[512];
    int t = threadIdx.x;
    for (int i = t; i < 512; i += 256) c[i] = 0;
    __syncthreads();
    int base = blockIdx.x * 4096;
    for (int i = t; i < 4096; i += 256) {
        int e = base + i;
        if (e < nE) atomicAdd(&c[dst[e] >> 8], 1);
    }
    __syncthreads();
    for (int i = t; i < 512; i += 256)
        if (c[i]) atomicAdd(&bucketCnt[i], c[i]);
}

__global__ __launch_bounds__(512) void bs_scan(const int* __restrict__ bucketCnt,
                                               int* __restrict__ bucketBase,
                                               int* __restrict__ bucketCur,
                                               int* __restrict__ off, int M, int nE) {
    __shared__ int s[512];
    int t = threadIdx.x;
    int v = bucketCnt[t];
    s[t] = v;
    __syncthreads();
    for (int o = 1; o < 512; o <<= 1) {
        int x = (t >= o) ? s[t - o] : 0;
        __syncthreads();
        s[t] += x;
        __syncthreads();
    }
    bucketBase[t] = s[t] - v;
    bucketCur[t] = s[t] - v;
    if (t == 511) bucketBase[512] = s[511];
    if (t == 0) off[M] = nE;
}

// packed entry: src (bits 0..16) | (dst&255)<<17
__global__ __launch_bounds__(512) void bs_scatter(const int* __restrict__ src,
                                                  const int* __restrict__ dst, int nE,
                                                  int* __restrict__ bucketCur,
                                                  unsigned int* __restrict__ ebuf) {
    __shared__ int cnt[512];
    __shared__ int excl[512];
    __shared__ int chunk[512];
    __shared__ unsigned int buf[4096];
    __shared__ unsigned short bkt[4096];
    int t = threadIdx.x;
    cnt[t] = 0;
    __syncthreads();
    int base = blockIdx.x * 4096;
    int n = nE - base; if (n > 4096) n = 4096;
    unsigned int pk[8]; int bk[8]; int rk[8];
#pragma unroll
    for (int u = 0; u < 8; ++u) {
        int i = t + u * 512;
        if (i < n) {
            int e = base + i;
            int d = dst[e];
            int b = d >> 8;
            bk[u] = b;
            pk[u] = (unsigned int)src[e] | ((unsigned int)(d & 255) << 17);
            rk[u] = atomicAdd(&cnt[b], 1);
        } else bk[u] = -1;
    }
    __syncthreads();
    excl[t] = cnt[t];
    __syncthreads();
    for (int o = 1; o < 512; o <<= 1) {
        int x = (t >= o) ? excl[t - o] : 0;
        __syncthreads();
        excl[t] += x;
        __syncthreads();
    }
    int ex = excl[t] - cnt[t];
    __syncthreads();
    excl[t] = ex;
    if (cnt[t]) chunk[t] = atomicAdd(&bucketCur[t], cnt[t]);
    __syncthreads();
#pragma unroll
    for (int u = 0; u < 8; ++u) {
        if (bk[u] >= 0) {
            int lp = excl[bk[u]] + rk[u];
            buf[lp] = pk[u];
            bkt[lp] = (unsigned short)bk[u];
        }
    }
    __syncthreads();
    for (int i = t; i < n; i += 512) {
        int b = bkt[i];
        ebuf[chunk[b] + (i - excl[b])] = buf[i];
    }
}

__global__ __launch_bounds__(512) void bs_build(const unsigned int* __restrict__ ebuf,
                                                const int* __restrict__ bucketBase,
                                                int* __restrict__ off,
                                                int* __restrict__ esrc, int M) {
    __shared__ int cnt[256];
    __shared__ int excl[256];
    __shared__ int obuf[5120];
    int t = threadIdx.x, b = blockIdx.x;
    int base = bucketBase[b];
    int n = bucketBase[b + 1] - base;
    if (t < 256) cnt[t] = 0;
    __syncthreads();
    unsigned int pk[10]; int dl[10]; int rk[10];
#pragma unroll
    for (int u = 0; u < 10; ++u) {
        int i = t + u * 512;
        if (i < n) {
            unsigned int p = ebuf[base + i];
            pk[u] = p;
            int d = (p >> 17) & 255;
            dl[u] = d;
            rk[u] = atomicAdd(&cnt[d], 1);
        } else dl[u] = -1;
    }
    __syncthreads();
    if (t < 256) excl[t] = cnt[t];
    __syncthreads();
    for (int o = 1; o < 256; o <<= 1) {
        int x = (t < 256 && t >= o) ? excl[t - o] : 0;
        __syncthreads();
        if (t < 256) excl[t] += x;
        __syncthreads();
    }
    if (t < 256) {
        int ex = excl[t] - cnt[t];
        int node = b * 256 + t;
        if (node < M) off[node] = base + ex;
        excl[t] = ex;
    }
    __syncthreads();
#pragma unroll
    for (int u = 0; u < 10; ++u) {
        if (dl[u] >= 0) {
            int lp = excl[dl[u]] + rk[u];
            if (lp < 5120) obuf[lp] = (int)(pk[u] & 0x1FFFF);
        }
    }
    __syncthreads();
    for (int i = t; i < n; i += 512) esrc[base + i] = obuf[i];
}

// ==== combined prep: weights fp32 W[k][n] -> bf16 transposed [n][k]; x -> bf16 ====
struct Prep {
    const float* W[6];
    unsigned short* hi[6];
    const float4* xin;
    uint2* xout;
    int n4;
};

__global__ __launch_bounds__(256) void k_prep(Prep p) {
    int b = blockIdx.x;
    if (b < 344) {
        int mat = b >> 6;             // mats 0..4: 64 blocks each; mat 5: blocks 320..343
        int rel = b - mat * 64;
        int NPAD = (mat == 5) ? 48 : 128;
        int N = (mat == 5) ? 40 : 128;
        int idx = rel * 256 + threadIdx.x;
        if (idx >= NPAD * 128) return;
        int n = idx >> 7, k = idx & 127;
        float w = (n < N) ? p.W[mat][k * N + n] : 0.f;
        p.hi[mat][idx] = f2bf(w);
    } else {
        int i = (b - 344) * 256 + threadIdx.x;
        if (i >= p.n4) return;
        float4 v = p.xin[i];
        uint2 o;
        o.x = ((unsigned int)f2bf(v.y) << 16) | f2bf(v.x);
        o.y = ((unsigned int)f2bf(v.w) << 16) | f2bf(v.z);
        p.xout[i] = o;
    }
}

// ======= aggregation: a = (1+eps)*h + sum_{j->i} h_j (h bf16) ; emit bf16 =======
// One node per 16-lane quarter (4 nodes/wave); uint4 (16 B) loads -> 128 B/lane in
// flight at 8-deep. Fast path unmasked; single predicated tail batch (clamped to
// last edge, masked to zero).
__device__ __forceinline__ void acc8(uint4 v, float* s) {
    float a, b;
    unpack2(v.x, a, b); s[0] += a; s[1] += b;
    unpack2(v.y, a, b); s[2] += a; s[3] += b;
    unpack2(v.z, a, b); s[4] += a; s[5] += b;
    unpack2(v.w, a, b); s[6] += a; s[7] += b;
}

__global__ __launch_bounds__(256) void k_aggr(const uint4* __restrict__ Hin,
                                              const int* __restrict__ off,
                                              const int* __restrict__ esrc,
                                              const float* __restrict__ epsp,
                                              uint4* __restrict__ Ahi, int M) {
    int w = threadIdx.x >> 6, lane = threadIdx.x & 63;
    int li = lane & 15, q = lane >> 4;
    int node = blockIdx.x * 16 + w * 4 + q;
    if (node >= M) return;
    float ep = 1.0f + epsp[0];
    uint4 ow = Hin[node * 16 + li];
    float s[8] = {0.f, 0.f, 0.f, 0.f, 0.f, 0.f, 0.f, 0.f};
    int i = off[node], e = off[node + 1];
    // fast path: full unmasked batches of 8
    for (; i + 8 <= e; i += 8) {
        uint4 v[8];
#pragma unroll
        for (int j = 0; j < 8; ++j) v[j] = Hin[esrc[i + j] * 16 + li];
#pragma unroll
        for (int j = 0; j < 8; ++j) acc8(v[j], s);
    }
    // tail: one predicated batch
    if (i < e) {
        int last = e - 1;
        uint4 v[8];
#pragma unroll
        for (int j = 0; j < 8; ++j) {
            int idx = i + j;
            int cl = idx < last ? idx : last;
            v[j] = Hin[esrc[cl] * 16 + li];
        }
#pragma unroll
        for (int j = 0; j < 8; ++j) {
            bool ok = (i + j) < e;
            uint4 u;
            u.x = ok ? v[j].x : 0u;
            u.y = ok ? v[j].y : 0u;
            u.z = ok ? v[j].z : 0u;
            u.w = ok ? v[j].w : 0u;
            acc8(u, s);
        }
    }
    float o[8];
    unpack2(ow.x, o[0], o[1]);
    unpack2(ow.y, o[2], o[3]);
    unpack2(ow.z, o[4], o[5]);
    unpack2(ow.w, o[6], o[7]);
#pragma unroll
    for (int k = 0; k < 8; ++k) s[k] = ep * o[k] + s[k];
    uint4 r;
    r.x = ((unsigned int)f2bf(s[1]) << 16) | f2bf(s[0]);
    r.y = ((unsigned int)f2bf(s[3]) << 16) | f2bf(s[2]);
    r.z = ((unsigned int)f2bf(s[5]) << 16) | f2bf(s[4]);
    r.w = ((unsigned int)f2bf(s[7]) << 16) | f2bf(s[6]);
    Ahi[node * 16 + li] = r;
}

// ============ fused 2-layer MLP, weights LDS-staged, 128 rows/block ============
// A bf16 [M][128]; W1h/W2h bf16 transposed [n][128].
// !LOGITS: HOut = bf16 [M][128] with relu; LOGITS: LOut = fp32 log_softmax [M][40].
template <int NT2, bool LOGITS>
__global__ __launch_bounds__(256, 3) void k_mlp(const unsigned short* __restrict__ AhiS,
                                                const unsigned short* __restrict__ W1h,
                                                const float* __restrict__ B1,
                                                const unsigned short* __restrict__ W2h,
                                                const float* __restrict__ B2,
                                                unsigned short* __restrict__ HOut,
                                                float* __restrict__ LOut, int M) {
    __shared__ short wbuf[128 * 136];     // 272 B row stride: b128-aligned, 2-way-free
    __shared__ short slab[4][16 * 136];   // wave-private transpose slab
    int t = threadIdx.x, w = t >> 6, lane = t & 63;
    int lm = lane & 15, lg = lane >> 4;
    int rbase = blockIdx.x * 128;

    // ---- stage W1h ----
    for (int i = t * 8; i < 128 * 128; i += 2048) {
        int n = i >> 7, k = i & 127;
        *(short8*)&wbuf[n * 136 + k] = *(const short8*)(W1h + i);
    }
    __syncthreads();

    short8 hh[2][4];
#pragma unroll
    for (int t2 = 0; t2 < 2; ++t2) {
        int r0 = rbase + t2 * 64 + w * 16;
        if (r0 < M) {   // wave-uniform
            const short* Ah = (const short*)AhiS + (r0 + lm) * 128 + lg * 8;
            short8 ah[4];
#pragma unroll
            for (int kb = 0; kb < 4; ++kb) ah[kb] = *(const short8*)(Ah + kb * 32);
            float4v acc[8];
#pragma unroll
            for (int nt = 0; nt < 8; ++nt) acc[nt] = (float4v){0.f, 0.f, 0.f, 0.f};
#pragma unroll
            for (int nt = 0; nt < 8; ++nt) {
#pragma unroll
                for (int kb = 0; kb < 4; ++kb) {
                    short8 wh = *(const short8*)&wbuf[(nt * 16 + lm) * 136 + kb * 32 + lg * 8];
                    acc[nt] = __builtin_amdgcn_mfma_f32_16x16x32_bf16(ah[kb], wh, acc[nt], 0, 0, 0);
                }
            }
            // bias + relu -> slab transpose (C-layout -> A-layout), bf16
#pragma unroll
            for (int nt = 0; nt < 8; ++nt) {
                float b = B1[nt * 16 + lm];
#pragma unroll
                for (int r = 0; r < 4; ++r) {
                    float v = acc[nt][r] + b;
                    v = v > 0.f ? v : 0.f;
                    slab[w][(lg * 4 + r) * 136 + nt * 16 + lm] = (short)f2bf(v);
                }
            }
#pragma unroll
            for (int kb = 0; kb < 4; ++kb)
                hh[t2][kb] = *(const short8*)&slab[w][lm * 136 + kb * 32 + lg * 8];
        }
    }

    __syncthreads();
    // ---- stage W2h over wbuf ----
    for (int i = t * 8; i < NT2 * 16 * 128; i += 2048) {
        int n = i >> 7, k = i & 127;
        *(short8*)&wbuf[n * 136 + k] = *(const short8*)(W2h + i);
    }
    __syncthreads();

#pragma unroll
    for (int t2 = 0; t2 < 2; ++t2) {
        int r0 = rbase + t2 * 64 + w * 16;
        if (r0 >= M) continue;   // wave-uniform, no barriers below
        float4v acc2[NT2];
#pragma unroll
        for (int nt = 0; nt < NT2; ++nt) acc2[nt] = (float4v){0.f, 0.f, 0.f, 0.f};
#pragma unroll
        for (int nt = 0; nt < NT2; ++nt) {
#pragma unroll
            for (int kb = 0; kb < 4; ++kb) {
                short8 wh = *(const short8*)&wbuf[(nt * 16 + lm) * 136 + kb * 32 + lg * 8];
                acc2[nt] = __builtin_amdgcn_mfma_f32_16x16x32_bf16(hh[t2][kb], wh, acc2[nt], 0, 0, 0);
            }
        }
        if (!LOGITS) {
#pragma unroll
            for (int nt = 0; nt < NT2; ++nt) {
                int col = nt * 16 + lm;
                float b = B2[col];
#pragma unroll
                for (int r = 0; r < 4; ++r) {
                    float v = acc2[nt][r] + b;
                    v = v > 0.f ? v : 0.f;
                    HOut[(r0 + lg * 4 + r) * 128 + col] = f2bf(v);
                }
            }
        } else {
            float vv[NT2][4];
#pragma unroll
            for (int nt = 0; nt < NT2; ++nt) {
                int col = nt * 16 + lm;
                bool valid = col < 40;
                float b = valid ? B2[col] : 0.f;
#pragma unroll
                for (int r = 0; r < 4; ++r)
                    vv[nt][r] = valid ? (acc2[nt][r] + b) : -1e30f;
            }
#pragma unroll
            for (int r = 0; r < 4; ++r) {
                float m = vv[0][r];
#pragma unroll
                for (int nt = 1; nt < NT2; ++nt) m = fmaxf(m, vv[nt][r]);
#pragma unroll
                for (int o = 8; o >= 1; o >>= 1) m = fmaxf(m, __shfl_xor(m, o, 64));
                float s = 0.f;
#pragma unroll
                for (int nt = 0; nt < NT2; ++nt)
                    s += (vv[nt][r] > -1e29f) ? expf(vv[nt][r] - m) : 0.f;
#pragma unroll
                for (int o = 8; o >= 1; o >>= 1) s += __shfl_xor(s, o, 64);
                float ls = m + logf(s);
                int row = r0 + lg * 4 + r;
#pragma unroll
                for (int nt = 0; nt < NT2; ++nt) {
                    int col = nt * 16 + lm;
                    if (col < 40) LOut[row * 40 + col] = vv[nt][r] - ls;
                }
            }
        }
    }
}

// ---------------- launch ----------------
extern "C" void kernel_launch(void* const* d_in, const int* in_sizes, int n_in,
                              void* d_out, int out_size, void* d_ws, size_t ws_size,
                              hipStream_t stream) {
    const float* x    = (const float*)d_in[0];
    const int*   edges = (const int*)d_in[1];
    const float* eps0 = (const float*)d_in[6];
    const float* eps1 = (const float*)d_in[11];
    const float* eps2 = (const float*)d_in[16];
    const float* B1[3] = {(const float*)d_in[3], (const float*)d_in[8], (const float*)d_in[13]};
    const float* B2[3] = {(const float*)d_in[5], (const float*)d_in[10], (const float*)d_in[15]};

    int M  = in_sizes[0] / 128;   // 100000
    int nE = in_sizes[1] / 2;     // 1600000
    const int* e_src = edges;
    const int* e_dst = edges + nE;

    char* ws = (char*)d_ws;
    size_t o = 0;
    auto alloc = [&](size_t bytes) {
        size_t p = o;
        o = (o + bytes + 511) & ~(size_t)511;
        return ws + p;
    };
    int* bucketCnt  = (int*)alloc(512 * 4);
    int* bucketBase = (int*)alloc(513 * 4);
    int* bucketCur  = (int*)alloc(512 * 4);
    int* off  = (int*)alloc((size_t)(M + 1) * 4);
    int* esrc = (int*)alloc((size_t)nE * 4);
    unsigned int* ebuf = (unsigned int*)alloc((size_t)nE * 4);

    Prep pp;
    pp.W[0] = (const float*)d_in[2];  pp.W[1] = (const float*)d_in[4];
    pp.W[2] = (const float*)d_in[7];  pp.W[3] = (const float*)d_in[9];
    pp.W[4] = (const float*)d_in[12]; pp.W[5] = (const float*)d_in[14];
    for (int m = 0; m < 6; ++m) {
        int npad = (m == 5) ? 48 : 128;
        pp.hi[m] = (unsigned short*)alloc((size_t)npad * 128 * 2);
    }
    unsigned short* xb  = (unsigned short*)alloc((size_t)M * 128 * 2);
    unsigned short* Ahi = (unsigned short*)alloc((size_t)M * 128 * 2);
    unsigned short* Hb  = (unsigned short*)alloc((size_t)M * 128 * 2);
    pp.xin = (const float4*)x;
    pp.xout = (uint2*)xb;
    pp.n4 = M * 32;
    (void)ws_size; (void)n_in; (void)out_size;

    hipMemsetAsync(bucketCnt, 0, 512 * 4, stream);
    int nChunk = (nE + 4095) / 4096;
    int nBk = (M + 255) / 256;
    bs_count<<<nChunk, 256, 0, stream>>>(e_dst, nE, bucketCnt);
    bs_scan<<<1, 512, 0, stream>>>(bucketCnt, bucketBase, bucketCur, off, M, nE);
    bs_scatter<<<nChunk, 512, 0, stream>>>(e_src, e_dst, nE, bucketCur, ebuf);
    bs_build<<<nBk, 512, 0, stream>>>(ebuf, bucketBase, off, esrc, M);
    k_prep<<<344 + (pp.n4 + 255) / 256, 256, 0, stream>>>(pp);

    int gA = (M + 15) / 16;      // 6250
    int gG = (M + 127) / 128;    // 782

    // layer 0
    k_aggr<<<gA, 256, 0, stream>>>((const uint4*)xb, off, esrc, eps0, (uint4*)Ahi, M);
    k_mlp<8, false><<<gG, 256, 0, stream>>>(Ahi, pp.hi[0], B1[0],
                                            pp.hi[1], B2[0], Hb, nullptr, M);
    // layer 1
    k_aggr<<<gA, 256, 0, stream>>>((const uint4*)Hb, off, esrc, eps1, (uint4*)Ahi, M);
    k_mlp<8, false><<<gG, 256, 0, stream>>>(Ahi, pp.hi[2], B1[1],
                                            pp.hi[3], B2[1], Hb, nullptr, M);
    // layer 2 (log_softmax fused)
    k_aggr<<<gA, 256, 0, stream>>>((const uint4*)Hb, off, esrc, eps2, (uint4*)Ahi, M);
    k_mlp<3, true><<<gG, 256, 0, stream>>>(Ahi, pp.hi[4], B1[2],
                                           pp.hi[5], B2[2], nullptr,
                                           (float*)d_out, M);
}

// Round 8
// 404.245 us; speedup vs baseline: 2.5869x; 1.0102x over previous
//
#include <hip/hip_runtime.h>
#include <stdint.h>

typedef __attribute__((ext_vector_type(8))) short short8;
typedef __attribute__((ext_vector_type(4))) short short4v;
typedef __attribute__((ext_vector_type(4))) float float4v;

__device__ __forceinline__ float bf2f(unsigned short s) {
    union { unsigned int u; float f; } c; c.u = ((unsigned int)s) << 16; return c.f;
}
__device__ __forceinline__ unsigned short f2bf(float f) {
    union { float f; unsigned int u; } c; c.f = f;
    unsigned int x = c.u;
    unsigned int r = x + 0x7fffu + ((x >> 16) & 1u);   // RNE
    return (unsigned short)(r >> 16);
}
__device__ __forceinline__ void unpack2(unsigned int u, float& lo, float& hi) {
    union { unsigned int uu; float ff; } a, b;
    a.uu = u << 16;          // low bf16
    b.uu = u & 0xffff0000u;  // high bf16
    lo = a.ff; hi = b.ff;
}

// ================= CSR build via bucket sort (bucket = dst>>8) =================
__global__ __launch_bounds__(256) void bs_count(const int* __restrict__ dst, int nE,
                                                int* __restrict__ bucketCnt) {
    __shared__ int c[512];
    int t = threadIdx.x;
    for (int i = t; i < 512; i += 256) c[i] = 0;
    __syncthreads();
    int base = blockIdx.x * 4096;
    for (int i = t; i < 4096; i += 256) {
        int e = base + i;
        if (e < nE) atomicAdd(&c[dst[e] >> 8], 1);
    }
    __syncthreads();
    for (int i = t; i < 512; i += 256)
        if (c[i]) atomicAdd(&bucketCnt[i], c[i]);
}

__global__ __launch_bounds__(512) void bs_scan(const int* __restrict__ bucketCnt,
                                               int* __restrict__ bucketBase,
                                               int* __restrict__ bucketCur,
                                               int* __restrict__ off, int M, int nE) {
    __shared__ int s[512];
    int t = threadIdx.x;
    int v = bucketCnt[t];
    s[t] = v;
    __syncthreads();
    for (int o = 1; o < 512; o <<= 1) {
        int x = (t >= o) ? s[t - o] : 0;
        __syncthreads();
        s[t] += x;
        __syncthreads();
    }
    bucketBase[t] = s[t] - v;
    bucketCur[t] = s[t] - v;
    if (t == 511) bucketBase[512] = s[511];
    if (t == 0) off[M] = nE;
}

// packed entry: src (bits 0..16) | (dst&255)<<17
__global__ __launch_bounds__(512) void bs_scatter(const int* __restrict__ src,
                                                  const int* __restrict__ dst, int nE,
                                                  int* __restrict__ bucketCur,
                                                  unsigned int* __restrict__ ebuf) {
    __shared__ int cnt[512];
    __shared__ int excl[512];
    __shared__ int chunk[512];
    __shared__ unsigned int buf[4096];
    __shared__ unsigned short bkt[4096];
    int t = threadIdx.x;
    cnt[t] = 0;
    __syncthreads();
    int base = blockIdx.x * 4096;
    int n = nE - base; if (n > 4096) n = 4096;
    unsigned int pk[8]; int bk[8]; int rk[8];
#pragma unroll
    for (int u = 0; u < 8; ++u) {
        int i = t + u * 512;
        if (i < n) {
            int e = base + i;
            int d = dst[e];
            int b = d >> 8;
            bk[u] = b;
            pk[u] = (unsigned int)src[e] | ((unsigned int)(d & 255) << 17);
            rk[u] = atomicAdd(&cnt[b], 1);
        } else bk[u] = -1;
    }
    __syncthreads();
    excl[t] = cnt[t];
    __syncthreads();
    for (int o = 1; o < 512; o <<= 1) {
        int x = (t >= o) ? excl[t - o] : 0;
        __syncthreads();
        excl[t] += x;
        __syncthreads();
    }
    int ex = excl[t] - cnt[t];
    __syncthreads();
    excl[t] = ex;
    if (cnt[t]) chunk[t] = atomicAdd(&bucketCur[t], cnt[t]);
    __syncthreads();
#pragma unroll
    for (int u = 0; u < 8; ++u) {
        if (bk[u] >= 0) {
            int lp = excl[bk[u]] + rk[u];
            buf[lp] = pk[u];
            bkt[lp] = (unsigned short)bk[u];
        }
    }
    __syncthreads();
    for (int i = t; i < n; i += 512) {
        int b = bkt[i];
        ebuf[chunk[b] + (i - excl[b])] = buf[i];
    }
}

__global__ __launch_bounds__(512) void bs_build(const unsigned int* __restrict__ ebuf,
                                                const int* __restrict__ bucketBase,
                                                int* __restrict__ off,
                                                int* __restrict__ esrc, int M) {
    __shared__ int cnt[256];
    __shared__ int excl[256];
    __shared__ int obuf[5120];
    int t = threadIdx.x, b = blockIdx.x;
    int base = bucketBase[b];
    int n = bucketBase[b + 1] - base;
    if (t < 256) cnt[t] = 0;
    __syncthreads();
    unsigned int pk[10]; int dl[10]; int rk[10];
#pragma unroll
    for (int u = 0; u < 10; ++u) {
        int i = t + u * 512;
        if (i < n) {
            unsigned int p = ebuf[base + i];
            pk[u] = p;
            int d = (p >> 17) & 255;
            dl[u] = d;
            rk[u] = atomicAdd(&cnt[d], 1);
        } else dl[u] = -1;
    }
    __syncthreads();
    if (t < 256) excl[t] = cnt[t];
    __syncthreads();
    for (int o = 1; o < 256; o <<= 1) {
        int x = (t < 256 && t >= o) ? excl[t - o] : 0;
        __syncthreads();
        if (t < 256) excl[t] += x;
        __syncthreads();
    }
    if (t < 256) {
        int ex = excl[t] - cnt[t];
        int node = b * 256 + t;
        if (node < M) off[node] = base + ex;
        excl[t] = ex;
    }
    __syncthreads();
#pragma unroll
    for (int u = 0; u < 10; ++u) {
        if (dl[u] >= 0) {
            int lp = excl[dl[u]] + rk[u];
            if (lp < 5120) obuf[lp] = (int)(pk[u] & 0x1FFFF);
        }
    }
    __syncthreads();
    for (int i = t; i < n; i += 512) esrc[base + i] = obuf[i];
}

// ==== combined prep: weights fp32 W[k][n] -> bf16 transposed [n][k]; x -> bf16 ====
struct Prep {
    const float* W[6];
    unsigned short* hi[6];
    const float4* xin;
    uint2* xout;
    int n4;
};

__global__ __launch_bounds__(256) void k_prep(Prep p) {
    int b = blockIdx.x;
    if (b < 344) {
        int mat = b >> 6;             // mats 0..4: 64 blocks each; mat 5: blocks 320..343
        int rel = b - mat * 64;
        int NPAD = (mat == 5) ? 48 : 128;
        int N = (mat == 5) ? 40 : 128;
        int idx = rel * 256 + threadIdx.x;
        if (idx >= NPAD * 128) return;
        int n = idx >> 7, k = idx & 127;
        float w = (n < N) ? p.W[mat][k * N + n] : 0.f;
        p.hi[mat][idx] = f2bf(w);
    } else {
        int i = (b - 344) * 256 + threadIdx.x;
        if (i >= p.n4) return;
        float4 v = p.xin[i];
        uint2 o;
        o.x = ((unsigned int)f2bf(v.y) << 16) | f2bf(v.x);
        o.y = ((unsigned int)f2bf(v.w) << 16) | f2bf(v.z);
        p.xout[i] = o;
    }
}

// ======= aggregation: a = (1+eps)*h + sum_{j->i} h_j (h bf16) ; emit bf16 =======
__device__ __forceinline__ void acc8(uint4 v, float* s) {
    float a, b;
    unpack2(v.x, a, b); s[0] += a; s[1] += b;
    unpack2(v.y, a, b); s[2] += a; s[3] += b;
    unpack2(v.z, a, b); s[4] += a; s[5] += b;
    unpack2(v.w, a, b); s[6] += a; s[7] += b;
}

__global__ __launch_bounds__(256) void k_aggr(const uint4* __restrict__ Hin,
                                              const int* __restrict__ off,
                                              const int* __restrict__ esrc,
                                              const float* __restrict__ epsp,
                                              uint4* __restrict__ Ahi, int M) {
    int w = threadIdx.x >> 6, lane = threadIdx.x & 63;
    int li = lane & 15, q = lane >> 4;
    int node = blockIdx.x * 16 + w * 4 + q;
    if (node >= M) return;
    float ep = 1.0f + epsp[0];
    uint4 ow = Hin[node * 16 + li];
    float s[8] = {0.f, 0.f, 0.f, 0.f, 0.f, 0.f, 0.f, 0.f};
    int i = off[node], e = off[node + 1];
    for (; i + 8 <= e; i += 8) {
        uint4 v[8];
#pragma unroll
        for (int j = 0; j < 8; ++j) v[j] = Hin[esrc[i + j] * 16 + li];
#pragma unroll
        for (int j = 0; j < 8; ++j) acc8(v[j], s);
    }
    if (i < e) {
        int last = e - 1;
        uint4 v[8];
#pragma unroll
        for (int j = 0; j < 8; ++j) {
            int idx = i + j;
            int cl = idx < last ? idx : last;
            v[j] = Hin[esrc[cl] * 16 + li];
        }
#pragma unroll
        for (int j = 0; j < 8; ++j) {
            bool ok = (i + j) < e;
            uint4 u;
            u.x = ok ? v[j].x : 0u;
            u.y = ok ? v[j].y : 0u;
            u.z = ok ? v[j].z : 0u;
            u.w = ok ? v[j].w : 0u;
            acc8(u, s);
        }
    }
    float o[8];
    unpack2(ow.x, o[0], o[1]);
    unpack2(ow.y, o[2], o[3]);
    unpack2(ow.z, o[4], o[5]);
    unpack2(ow.w, o[6], o[7]);
#pragma unroll
    for (int k = 0; k < 8; ++k) s[k] = ep * o[k] + s[k];
    uint4 r;
    r.x = ((unsigned int)f2bf(s[1]) << 16) | f2bf(s[0]);
    r.y = ((unsigned int)f2bf(s[3]) << 16) | f2bf(s[2]);
    r.z = ((unsigned int)f2bf(s[5]) << 16) | f2bf(s[4]);
    r.w = ((unsigned int)f2bf(s[7]) << 16) | f2bf(s[6]);
    Ahi[node * 16 + li] = r;
}

// ============ fused 2-layer MLP, transpose-free (Hᵀ trick), 128 rows/block ============
// GEMM1: D1 = mfma16x16x32(a=W1-frag, b=X-frag) -> D1[m=hidden][n=node] in C-layout:
//   lane (lm,lg) holds H[node=lm][hidden=nt*16+lg*4+r].  That register layout IS the
//   B-operand layout of mfma_f32_16x16x16_bf16 (k = lg*4+i), so GEMM2 consumes the
//   packed relu(H) fragments directly -- no LDS transpose, no slab.
// !LOGITS: HOut bf16 [M][128] (relu); LOGITS: LOut fp32 log_softmax [M][40].
template <int NT2, bool LOGITS>
__global__ __launch_bounds__(256, 4) void k_mlp(const unsigned short* __restrict__ AhiS,
                                                const unsigned short* __restrict__ W1h,
                                                const float* __restrict__ B1,
                                                const unsigned short* __restrict__ W2h,
                                                const float* __restrict__ B2,
                                                unsigned short* __restrict__ HOut,
                                                float* __restrict__ LOut, int M) {
    __shared__ short wbuf[128 * 136];     // 272 B row stride
    int t = threadIdx.x, w = t >> 6, lane = t & 63;
    int lm = lane & 15, lg = lane >> 4;
    int rbase = blockIdx.x * 128;

    // ---- stage W1h ----
    for (int i = t * 8; i < 128 * 128; i += 2048) {
        int n = i >> 7, k = i & 127;
        *(short8*)&wbuf[n * 136 + k] = *(const short8*)(W1h + i);
    }
    __syncthreads();

    // ---- GEMM1 (both 64-row halves), pack H fragments in registers ----
    short4v h2[2][8];
    bool act[2];
#pragma unroll
    for (int t2 = 0; t2 < 2; ++t2) {
        int r0 = rbase + t2 * 64 + w * 16;
        act[t2] = (r0 < M);                    // wave-uniform (M % 16 == 0)
        if (act[t2]) {
            const short* Xp = (const short*)AhiS + (r0 + lm) * 128 + lg * 8;
            short8 xf[4];
#pragma unroll
            for (int kb = 0; kb < 4; ++kb) xf[kb] = *(const short8*)(Xp + kb * 32);
            float4v acc1[8];
#pragma unroll
            for (int nt = 0; nt < 8; ++nt) acc1[nt] = (float4v){0.f, 0.f, 0.f, 0.f};
#pragma unroll
            for (int nt = 0; nt < 8; ++nt) {
#pragma unroll
                for (int kb = 0; kb < 4; ++kb) {
                    short8 wf = *(const short8*)&wbuf[(nt * 16 + lm) * 136 + kb * 32 + lg * 8];
                    // a = weight frag, b = node frag  ->  D = H^T
                    acc1[nt] = __builtin_amdgcn_mfma_f32_16x16x32_bf16(wf, xf[kb], acc1[nt], 0, 0, 0);
                }
            }
#pragma unroll
            for (int nt = 0; nt < 8; ++nt) {
                float4 b1 = *(const float4*)(B1 + nt * 16 + lg * 4);
                float v0 = acc1[nt][0] + b1.x; v0 = v0 > 0.f ? v0 : 0.f;
                float v1 = acc1[nt][1] + b1.y; v1 = v1 > 0.f ? v1 : 0.f;
                float v2 = acc1[nt][2] + b1.z; v2 = v2 > 0.f ? v2 : 0.f;
                float v3 = acc1[nt][3] + b1.w; v3 = v3 > 0.f ? v3 : 0.f;
                h2[t2][nt] = (short4v){(short)f2bf(v0), (short)f2bf(v1),
                                       (short)f2bf(v2), (short)f2bf(v3)};
            }
        } else {
#pragma unroll
            for (int nt = 0; nt < 8; ++nt) h2[t2][nt] = (short4v){0, 0, 0, 0};
        }
    }

    __syncthreads();
    // ---- stage W2h over wbuf ----
    for (int i = t * 8; i < NT2 * 16 * 128; i += 2048) {
        int n = i >> 7, k = i & 127;
        *(short8*)&wbuf[n * 136 + k] = *(const short8*)(W2h + i);
    }
    __syncthreads();

    // ---- GEMM2: K=16 MFMAs consume h2 directly ----
    float4v acc2[2][NT2];
#pragma unroll
    for (int t2 = 0; t2 < 2; ++t2)
#pragma unroll
        for (int ot = 0; ot < NT2; ++ot) acc2[t2][ot] = (float4v){0.f, 0.f, 0.f, 0.f};
#pragma unroll
    for (int ot = 0; ot < NT2; ++ot) {
#pragma unroll
        for (int nt = 0; nt < 8; ++nt) {
            short4v wf = *(const short4v*)&wbuf[(ot * 16 + lm) * 136 + nt * 16 + lg * 4];
#pragma unroll
            for (int t2 = 0; t2 < 2; ++t2)
                acc2[t2][ot] = __builtin_amdgcn_mfma_f32_16x16x16bf16_1k(wf, h2[t2][nt],
                                                                         acc2[t2][ot], 0, 0, 0);
        }
    }

    // ---- epilogue: lane owns node (r0+lm), hidden units ot*16+lg*4+{0..3} ----
#pragma unroll
    for (int t2 = 0; t2 < 2; ++t2) {
        if (!act[t2]) continue;
        int row = rbase + t2 * 64 + w * 16 + lm;
        if (!LOGITS) {
#pragma unroll
            for (int ot = 0; ot < NT2; ++ot) {
                float4 b2 = *(const float4*)(B2 + ot * 16 + lg * 4);
                float v0 = acc2[t2][ot][0] + b2.x; v0 = v0 > 0.f ? v0 : 0.f;
                float v1 = acc2[t2][ot][1] + b2.y; v1 = v1 > 0.f ? v1 : 0.f;
                float v2 = acc2[t2][ot][2] + b2.z; v2 = v2 > 0.f ? v2 : 0.f;
                float v3 = acc2[t2][ot][3] + b2.w; v3 = v3 > 0.f ? v3 : 0.f;
                uint2 pk;
                pk.x = ((unsigned int)f2bf(v1) << 16) | f2bf(v0);
                pk.y = ((unsigned int)f2bf(v3) << 16) | f2bf(v2);
                *(uint2*)(HOut + row * 128 + ot * 16 + lg * 4) = pk;
            }
        } else {
            float vv[NT2][4];
#pragma unroll
            for (int ot = 0; ot < NT2; ++ot) {
                int ub = ot * 16 + lg * 4;
                bool valid = ub <= 36;     // units come in aligned 4-chunks; 40 total
                float4 b2 = valid ? *(const float4*)(B2 + ub) : (float4){0.f, 0.f, 0.f, 0.f};
                vv[ot][0] = valid ? acc2[t2][ot][0] + b2.x : -1e30f;
                vv[ot][1] = valid ? acc2[t2][ot][1] + b2.y : -1e30f;
                vv[ot][2] = valid ? acc2[t2][ot][2] + b2.z : -1e30f;
                vv[ot][3] = valid ? acc2[t2][ot][3] + b2.w : -1e30f;
            }
            float m = -1e30f;
#pragma unroll
            for (int ot = 0; ot < NT2; ++ot)
#pragma unroll
                for (int r = 0; r < 4; ++r) m = fmaxf(m, vv[ot][r]);
            m = fmaxf(m, __shfl_xor(m, 16, 64));
            m = fmaxf(m, __shfl_xor(m, 32, 64));
            float s = 0.f;
#pragma unroll
            for (int ot = 0; ot < NT2; ++ot)
#pragma unroll
                for (int r = 0; r < 4; ++r)
                    s += (vv[ot][r] > -1e29f) ? expf(vv[ot][r] - m) : 0.f;
            s += __shfl_xor(s, 16, 64);
            s += __shfl_xor(s, 32, 64);
            float ls = m + logf(s);
#pragma unroll
            for (int ot = 0; ot < NT2; ++ot) {
                int ub = ot * 16 + lg * 4;
                if (ub <= 36) {
                    float4 outv = {vv[ot][0] - ls, vv[ot][1] - ls,
                                   vv[ot][2] - ls, vv[ot][3] - ls};
                    *(float4*)(LOut + row * 40 + ub) = outv;
                }
            }
        }
    }
}

// ---------------- launch ----------------
extern "C" void kernel_launch(void* const* d_in, const int* in_sizes, int n_in,
                              void* d_out, int out_size, void* d_ws, size_t ws_size,
                              hipStream_t stream) {
    const float* x    = (const float*)d_in[0];
    const int*   edges = (const int*)d_in[1];
    const float* eps0 = (const float*)d_in[6];
    const float* eps1 = (const float*)d_in[11];
    const float* eps2 = (const float*)d_in[16];
    const float* B1[3] = {(const float*)d_in[3], (const float*)d_in[8], (const float*)d_in[13]};
    const float* B2[3] = {(const float*)d_in[5], (const float*)d_in[10], (const float*)d_in[15]};

    int M  = in_sizes[0] / 128;   // 100000
    int nE = in_sizes[1] / 2;     // 1600000
    const int* e_src = edges;
    const int* e_dst = edges + nE;

    char* ws = (char*)d_ws;
    size_t o = 0;
    auto alloc = [&](size_t bytes) {
        size_t p = o;
        o = (o + bytes + 511) & ~(size_t)511;
        return ws + p;
    };
    int* bucketCnt  = (int*)alloc(512 * 4);
    int* bucketBase = (int*)alloc(513 * 4);
    int* bucketCur  = (int*)alloc(512 * 4);
    int* off  = (int*)alloc((size_t)(M + 1) * 4);
    int* esrc = (int*)alloc((size_t)nE * 4);
    unsigned int* ebuf = (unsigned int*)alloc((size_t)nE * 4);

    Prep pp;
    pp.W[0] = (const float*)d_in[2];  pp.W[1] = (const float*)d_in[4];
    pp.W[2] = (const float*)d_in[7];  pp.W[3] = (const float*)d_in[9];
    pp.W[4] = (const float*)d_in[12]; pp.W[5] = (const float*)d_in[14];
    for (int m = 0; m < 6; ++m) {
        int npad = (m == 5) ? 48 : 128;
        pp.hi[m] = (unsigned short*)alloc((size_t)npad * 128 * 2);
    }
    unsigned short* xb  = (unsigned short*)alloc((size_t)M * 128 * 2);
    unsigned short* Ahi = (unsigned short*)alloc((size_t)M * 128 * 2);
    unsigned short* Hb  = (unsigned short*)alloc((size_t)M * 128 * 2);
    pp.xin = (const float4*)x;
    pp.xout = (uint2*)xb;
    pp.n4 = M * 32;
    (void)ws_size; (void)n_in; (void)out_size;

    hipMemsetAsync(bucketCnt, 0, 512 * 4, stream);
    int nChunk = (nE + 4095) / 4096;
    int nBk = (M + 255) / 256;
    bs_count<<<nChunk, 256, 0, stream>>>(e_dst, nE, bucketCnt);
    bs_scan<<<1, 512, 0, stream>>>(bucketCnt, bucketBase, bucketCur, off, M, nE);
    bs_scatter<<<nChunk, 512, 0, stream>>>(e_src, e_dst, nE, bucketCur, ebuf);
    bs_build<<<nBk, 512, 0, stream>>>(ebuf, bucketBase, off, esrc, M);
    k_prep<<<344 + (pp.n4 + 255) / 256, 256, 0, stream>>>(pp);

    int gA = (M + 15) / 16;      // 6250
    int gG = (M + 127) / 128;    // 782

    // layer 0
    k_aggr<<<gA, 256, 0, stream>>>((const uint4*)xb, off, esrc, eps0, (uint4*)Ahi, M);
    k_mlp<8, false><<<gG, 256, 0, stream>>>(Ahi, pp.hi[0], B1[0],
                                            pp.hi[1], B2[0], Hb, nullptr, M);
    // layer 1
    k_aggr<<<gA, 256, 0, stream>>>((const uint4*)Hb, off, esrc, eps1, (uint4*)Ahi, M);
    k_mlp<8, false><<<gG, 256, 0, stream>>>(Ahi, pp.hi[2], B1[1],
                                            pp.hi[3], B2[1], Hb, nullptr, M);
    // layer 2 (log_softmax fused)
    k_aggr<<<gA, 256, 0, stream>>>((const uint4*)Hb, off, esrc, eps2, (uint4*)Ahi, M);
    k_mlp<3, true><<<gG, 256, 0, stream>>>(Ahi, pp.hi[4], B1[2],
                                           pp.hi[5], B2[2], nullptr,
                                           (float*)d_out, M);
}